// Round 3
// baseline (484.990 us; speedup 1.0000x reference)
//
#include <hip/hip_runtime.h>

#define TWO_PI_F 6.28318530717958647692f
#define SCL_F    0.02209708691207961f   // TEMP/SCALE/sqrt(128)

__device__ __forceinline__ float rlane(float v, int l) {
    return __uint_as_float((unsigned)__builtin_amdgcn_readlane((int)__float_as_uint(v), l));
}

// ---------------------------------------------------------------------------
// Group-norm partial stats for in_f: per (b,g) over 16384 rows x 32 ch.
// grid=(64,32), block=256
// ---------------------------------------------------------------------------
__global__ __launch_bounds__(256) void gn_partial_k(const float* __restrict__ X,
                                                    float* __restrict__ partials)
{
    int t = threadIdx.x;
    int chunk = blockIdx.x;
    int grp = blockIdx.y;          // b*4+g
    int b = grp >> 2, g = grp & 3;
    const float* base = X + ((long)b * 16384 + (long)chunk * 256) * 128 + g * 32;
    float s = 0.f, ss = 0.f;
#pragma unroll
    for (int i = 0; i < 8; i++) {
        int rl_ = i * 32 + (t >> 3);
        int c4 = (t & 7) * 4;
        float4 v = *(const float4*)(base + (long)rl_ * 128 + c4);
        s  += v.x + v.y + v.z + v.w;
        ss += v.x * v.x + v.y * v.y + v.z * v.z + v.w * v.w;
    }
    __shared__ float r0[256], r1[256];
    r0[t] = s; r1[t] = ss;
    __syncthreads();
    for (int off = 128; off > 0; off >>= 1) {
        if (t < off) { r0[t] += r0[t + off]; r1[t] += r1[t + off]; }
        __syncthreads();
    }
    if (t == 0) {
        partials[(grp * 64 + chunk) * 2]     = r0[0];
        partials[(grp * 64 + chunk) * 2 + 1] = r1[0];
    }
}

// grid=32, block=64; nblk partials per group
__global__ void gn_final_k(const float* __restrict__ partials, float* __restrict__ stats,
                           int nblk)
{
    int grp = blockIdx.x, t = threadIdx.x;
    float s = 0.f, ss = 0.f;
    for (int i = t; i < nblk; i += 64) {
        s  += partials[(grp * nblk + i) * 2];
        ss += partials[(grp * nblk + i) * 2 + 1];
    }
    for (int off = 1; off < 64; off <<= 1) { s += __shfl_xor(s, off); ss += __shfl_xor(ss, off); }
    if (t == 0) {
        const float N = 524288.0f;
        float mu = s / N;
        float var = ss / N - mu * mu;
        stats[grp * 2]     = mu;
        stats[grp * 2 + 1] = 1.0f / sqrtf(var + 0.001f);
    }
}

// ---------------------------------------------------------------------------
// Wvf = Wv @ Wfc  (128x128). grid=32 blocks x 256 threads (4 rows/block).
// ---------------------------------------------------------------------------
__global__ __launch_bounds__(256) void wvf_prep_k(const float* __restrict__ Wv,
                                                  const float* __restrict__ Wfc,
                                                  float* __restrict__ out)
{
    int t = threadIdx.x;
    int rr = t >> 6, cl = t & 63;
    int r = blockIdx.x * 4 + rr;
    float a0 = 0.f, a1 = 0.f;
    for (int k = 0; k < 128; k++) {
        float wv = Wv[r * 128 + k];
        a0 = fmaf(wv, Wfc[k * 128 + cl], a0);
        a1 = fmaf(wv, Wfc[k * 128 + 64 + cl], a1);
    }
    out[r * 128 + cl] = a0;
    out[r * 128 + 64 + cl] = a1;
}

// ---------------------------------------------------------------------------
// Fused dual GEMM: A = gn1(in_f) tile staged ONCE; waves 0/1 compute
// C1 = leaky(A@W1 + b1) -> h1; waves 2/3 compute C2 = A@Wq -> qraw (+ fused
// stats2 partials from acc). grid=1024 (128 rows/block), block=256.
// v3: sRed aliased onto sA (dead after the K-loop) -> LDS 54,784 -> 50,688 B,
// crossing the 53,333 B threshold: 2 -> 3 blocks/CU (8 -> 12 waves/CU).
// __launch_bounds__(256,3) to match (VGPR 120 <= 170 cap, no spill risk).
// ---------------------------------------------------------------------------
__global__ __launch_bounds__(256, 3) void gemm256_fused(const float* __restrict__ X,
                                                        const float* __restrict__ W1,
                                                        const float* __restrict__ b1,
                                                        const float* __restrict__ Wq,
                                                        const float* __restrict__ stats,
                                                        float* __restrict__ C1,
                                                        float* __restrict__ C2,
                                                        float* __restrict__ statsout)
{
    __shared__ float sA[32 * 132];
    __shared__ float sB[2][32 * 132];
    float* sRed = sA;                // alias: sA is dead after the K-loop
    int t = threadIdx.x;
    int hw = t >> 7, ht = t & 127;   // hw: 0 -> W1 path, 1 -> Wq path
    long row0 = (long)blockIdx.x * 128;
    int bidx = (int)(row0 >> 14);

    float muv[4], rsv[4];
#pragma unroll
    for (int g = 0; g < 4; g++) {
        muv[g] = stats[(bidx * 4 + g) * 2];
        rsv[g] = stats[(bidx * 4 + g) * 2 + 1];
    }
    int rg = ht >> 3, cg = ht & 7;
    float acc[8][16];
#pragma unroll
    for (int i = 0; i < 8; i++)
#pragma unroll
        for (int j = 0; j < 16; j++) acc[i][j] = 0.f;

    const float* xs = X + (row0 + ht) * 128;
    int kb = ht >> 2, c0 = (ht & 3) * 32;

    for (int kt = 0; kt < 4; kt++) {
        if (hw == 0) {
            // stage A transposed + normalized (k-range [32kt,32kt+32) == group kt)
            float mu = muv[kt], rs = rsv[kt];
            const float* asrc = xs + kt * 32;
#pragma unroll
            for (int q = 0; q < 8; q++) {
                float4 v = *(const float4*)(asrc + 4 * q);
                sA[(4 * q + 0) * 132 + ht] = (v.x - mu) * rs;
                sA[(4 * q + 1) * 132 + ht] = (v.y - mu) * rs;
                sA[(4 * q + 2) * 132 + ht] = (v.z - mu) * rs;
                sA[(4 * q + 3) * 132 + ht] = (v.w - mu) * rs;
            }
        } else {
            // stage both B tiles
            const float* bsrc1 = W1 + (long)(kt * 32 + kb) * 128 + c0;
            const float* bsrc2 = Wq + (long)(kt * 32 + kb) * 128 + c0;
#pragma unroll
            for (int q = 0; q < 8; q++)
                *(float4*)&sB[0][kb * 132 + c0 + 4 * q] = *(const float4*)(bsrc1 + 4 * q);
#pragma unroll
            for (int q = 0; q < 8; q++)
                *(float4*)&sB[1][kb * 132 + c0 + 4 * q] = *(const float4*)(bsrc2 + 4 * q);
        }
        __syncthreads();
        const float* sBh = sB[hw];
#pragma unroll 4
        for (int k = 0; k < 32; k++) {
            float4 a0 = *(const float4*)&sA[k * 132 + rg * 8];
            float4 a1 = *(const float4*)&sA[k * 132 + rg * 8 + 4];
            float b[16];
#pragma unroll
            for (int m = 0; m < 4; m++) {
                float4 bv = *(const float4*)&sBh[k * 132 + cg * 4 + 32 * m];
                b[m * 4 + 0] = bv.x; b[m * 4 + 1] = bv.y;
                b[m * 4 + 2] = bv.z; b[m * 4 + 3] = bv.w;
            }
            float a[8] = {a0.x, a0.y, a0.z, a0.w, a1.x, a1.y, a1.z, a1.w};
#pragma unroll
            for (int i = 0; i < 8; i++)
#pragma unroll
                for (int j = 0; j < 16; j++)
                    acc[i][j] = fmaf(a[i], b[j], acc[i][j]);
        }
        __syncthreads();
    }

    float bv16[16];
#pragma unroll
    for (int m = 0; m < 4; m++)
#pragma unroll
        for (int j = 0; j < 4; j++)
            bv16[m * 4 + j] = (hw == 0) ? b1[cg * 4 + 32 * m + j] : 0.f;
    float* C = hw ? C2 : C1;
#pragma unroll
    for (int i = 0; i < 8; i++) {
        long r = row0 + rg * 8 + i;
#pragma unroll
        for (int m = 0; m < 4; m++) {
            float4 o;
            o.x = acc[i][m * 4 + 0] + bv16[m * 4 + 0];
            o.y = acc[i][m * 4 + 1] + bv16[m * 4 + 1];
            o.z = acc[i][m * 4 + 2] + bv16[m * 4 + 2];
            o.w = acc[i][m * 4 + 3] + bv16[m * 4 + 3];
            if (hw == 0) {
                o.x = (o.x >= 0.f) ? o.x : 0.01f * o.x;
                o.y = (o.y >= 0.f) ? o.y : 0.01f * o.y;
                o.z = (o.z >= 0.f) ? o.z : 0.01f * o.z;
                o.w = (o.w >= 0.f) ? o.w : 0.01f * o.w;
            }
            *(float4*)(C + r * 128 + cg * 4 + 32 * m) = o;
        }
    }
    // fused gn2 partial stats from the Wq half (stored value == acc there)
    if (hw == 1) {
        float s[4] = {0.f, 0.f, 0.f, 0.f}, ss[4] = {0.f, 0.f, 0.f, 0.f};
#pragma unroll
        for (int i = 0; i < 8; i++)
#pragma unroll
            for (int m = 0; m < 4; m++)
#pragma unroll
                for (int j = 0; j < 4; j++) {
                    float v = acc[i][m * 4 + j];
                    s[m] += v; ss[m] += v * v;
                }
#pragma unroll
        for (int m = 0; m < 4; m++) {
            sRed[ht * 8 + 2 * m]     = s[m];
            sRed[ht * 8 + 2 * m + 1] = ss[m];
        }
    }
    __syncthreads();
    if (hw == 1 && ht < 8) {
        int g = ht >> 1, which = ht & 1;
        float a2 = 0.f;
        for (int u = 0; u < 128; u++) a2 += sRed[u * 8 + 2 * g + which];
        statsout[((bidx * 4 + g) * 128 + (int)(blockIdx.x & 127)) * 2 + which] = a2;
    }
}

// ---------------------------------------------------------------------------
// attn: q = gn2(qraw) -> outQ; S = sq_dist(q,q); softmax; min-max -> af
// grid=1024 (2 windows/block), block=256 (128 threads/window, 8x4 tiles).
// sQ XOR-swizzled for conflict-free b128; S aliased into sQ after QK.
// Safe to run IN PLACE (Qraw == outQ): each float4 is read then written by
// the same thread.
// ---------------------------------------------------------------------------
__global__ __launch_bounds__(256, 2) void attn_v2(const float* __restrict__ Qraw,
                                                  const float* __restrict__ stats,
                                                  float* __restrict__ outQ,
                                                  float* __restrict__ outAF)
{
    __shared__ float sQ[2][8192];
    __shared__ float sN[2][64];
    int t = threadIdx.x;
    int wl = t >> 7;               // window half
    int tl = t & 127;
    int w = blockIdx.x * 2 + wl;
    int bidx = w >> 8;
    float muv[4], rsv[4];
#pragma unroll
    for (int g = 0; g < 4; g++) {
        muv[g] = stats[(bidx * 4 + g) * 2];
        rsv[g] = stats[(bidx * 4 + g) * 2 + 1];
    }
    // stage (normalize, write q out, swizzled LDS write)
    {
        int r = tl >> 1, q0 = (tl & 1) * 16;
        int sw = r >> 3;
        const float* src = Qraw + (long)w * 8192 + r * 128 + q0 * 4;
        float* dstG = outQ + (long)w * 8192 + r * 128 + q0 * 4;
#pragma unroll
        for (int q = 0; q < 16; q++) {
            float4 v = *(const float4*)(src + 4 * q);
            int g = (q0 + q) >> 3;
            float mu = muv[g], rs = rsv[g];
            v.x = (v.x - mu) * rs; v.y = (v.y - mu) * rs;
            v.z = (v.z - mu) * rs; v.w = (v.w - mu) * rs;
            *(float4*)(dstG + 4 * q) = v;
            *(float4*)&sQ[wl][r * 128 + 4 * ((q0 + q) ^ sw)] = v;
        }
    }
    __syncthreads();
    if (tl < 64) {
        int r = tl, sw = r >> 3;
        float s = 0.f;
#pragma unroll
        for (int q = 0; q < 32; q++) {
            float4 v = *(const float4*)&sQ[wl][r * 128 + 4 * (q ^ sw)];
            s += v.x * v.x + v.y * v.y + v.z * v.z + v.w * v.w;
        }
        sN[wl][r] = s;
    }
    __syncthreads();
    // QK: rows ty*8+i, cols tx*4+bb
    int ty = tl >> 4, tx = tl & 15;
    float acc[8][4];
#pragma unroll
    for (int i = 0; i < 8; i++)
#pragma unroll
        for (int bb = 0; bb < 4; bb++) acc[i][bb] = 0.f;
    for (int kq = 0; kq < 32; kq++) {
        float4 bf[4];
#pragma unroll
        for (int bb = 0; bb < 4; bb++) {
            int col = tx * 4 + bb;
            bf[bb] = *(const float4*)&sQ[wl][col * 128 + 4 * (kq ^ (col >> 3))];
        }
#pragma unroll
        for (int i = 0; i < 8; i++) {
            int row = ty * 8 + i;
            float4 av = *(const float4*)&sQ[wl][row * 128 + 4 * (kq ^ (row >> 3))];
#pragma unroll
            for (int bb = 0; bb < 4; bb++)
                acc[i][bb] += av.x * bf[bb].x + av.y * bf[bb].y
                            + av.z * bf[bb].z + av.w * bf[bb].w;
        }
    }
    __syncthreads();                 // done reading sQ
    float* sS = &sQ[wl][0];          // alias, stride 65
#pragma unroll
    for (int i = 0; i < 8; i++) {
        int row = ty * 8 + i;
#pragma unroll
        for (int bb = 0; bb < 4; bb++) {
            int col = tx * 4 + bb;
            sS[row * 65 + col] = sN[wl][row] + sN[wl][col] - 2.f * acc[i][bb];
        }
    }
    __syncthreads();
    // epilogue: lane = row, serial over j (no shuffles)
    if (tl < 64) {
        int r = tl;
        float mnS = sS[r * 65];
        for (int j = 1; j < 64; j++) mnS = fminf(mnS, sS[r * 65 + j]);
        float sum = 0.f, pmx = -1.f, pmn = 1e30f;
        for (int j = 0; j < 64; j++) {
            float p = expf(-SCL_F * (sS[r * 65 + j] - mnS));
            sS[r * 65 + j] = p;
            sum += p;
            pmx = fmaxf(pmx, p);
            pmn = fminf(pmn, p);
        }
        float rsum = 1.0f / sum;
        float amn = pmn * rsum, amx = pmx * rsum;
        float dinv = 1.0f / (amx - amn + 1e-8f);
        float* dst = outAF + (long)w * 4096 + r * 64;
        for (int j = 0; j < 64; j += 4) {
            float4 o;
            o.x = (sS[r * 65 + j + 0] * rsum - amn) * dinv;
            o.y = (sS[r * 65 + j + 1] * rsum - amn) * dinv;
            o.z = (sS[r * 65 + j + 2] * rsum - amn) * dinv;
            o.w = (sS[r * 65 + j + 3] * rsum - amn) * dinv;
            *(float4*)(dst + j) = o;
        }
    }
}

// ---------------------------------------------------------------------------
// Per-window clustering, register/readlane rewrite (DS-minimized).
// lane = row q; wave wv owns k = 4kk+wv (registers dk,ak,T[16]).
// Pair sum via min-identity; j<k handled by quad decomposition with
// wave-uniform branches. grid=2048, block=256.
// ---------------------------------------------------------------------------
__global__ __launch_bounds__(256, 4) void cluster_v3(const float* __restrict__ AF,
                                                     const float* __restrict__ GEO,
                                                     float* __restrict__ oCLM,
                                                     float* __restrict__ oCLR,
                                                     float* __restrict__ oCOMP,
                                                     float* __restrict__ oGEO,
                                                     float* __restrict__ oSCM,
                                                     float* __restrict__ wCLMM)
{
    __shared__ float sAF[64 * 65];
    __shared__ float sPart[4 * 64 * 3];
    __shared__ float sCLM[8 * 65];
    int t = threadIdx.x, w = blockIdx.x;
    int wv = t >> 6, lane = t & 63;
    const float* afw = AF + (long)w * 4096;
#pragma unroll
    for (int i = 0; i < 4; i++) {
        int f4 = i * 256 + t;
        float4 v = *(const float4*)(afw + f4 * 4);
        int r = f4 >> 4, c4 = (f4 & 15) * 4;
        float* dst = &sAF[r * 65 + c4];
        dst[0] = fminf(fmaxf(v.x, 1e-5f), 0.99999f);
        dst[1] = fminf(fmaxf(v.y, 1e-5f), 0.99999f);
        dst[2] = fminf(fmaxf(v.z, 1e-5f), 0.99999f);
        dst[3] = fminf(fmaxf(v.w, 1e-5f), 0.99999f);
    }
    // per-lane geo row (lane = element index)
    const float* gp = GEO + ((long)w * 64 + lane) * 6;
    float2 g01 = *(const float2*)(gp);
    float2 g23 = *(const float2*)(gp + 2);
    float2 g45 = *(const float2*)(gp + 4);
    float gD = g01.x, gA = g23.x, gI = g23.y, gX = g45.x, gY = g45.y;
    __syncthreads();

    // ---- phase 1 ----
    const float* afrow = &sAF[lane * 65];
    float dk[16], ak[16], T[16];
    float v0 = 0.f, v1 = 0.f;
#pragma unroll
    for (int kk = 0; kk < 16; kk++) {
        int kc = kk * 4 + wv;
        float afk = afrow[kc];
        float d = afk * rlane(gD, kc);
        float a = afk * rlane(gA, kc);
        dk[kk] = d; ak[kk] = a; T[kk] = 0.f;
        float m = d * a;
        float dx = gX - rlane(gX, kc), dy = gY - rlane(gY, kc);
        v0 += d * rlane(gI, kc) + m * (dx * dx + dy * dy);
        v1 += m * a;
    }
    for (int jq = 0; jq < 16; jq++) {
        float dj[4], aj[4];
#pragma unroll
        for (int jr = 0; jr < 4; jr++) {
            int j = jq * 4 + jr;
            float afj = afrow[j];
            dj[jr] = afj * rlane(gD, j);
            aj[jr] = afj * rlane(gA, j);
        }
#pragma unroll
        for (int kk = 0; kk < 16; kk++) {
            if (kk > jq) {
#pragma unroll
                for (int jr = 0; jr < 4; jr++)
                    T[kk] = fmaf(aj[jr], fminf(dj[jr], dk[kk]), T[kk]);
            } else if (kk == jq) {
                if (0 < wv) T[kk] = fmaf(aj[0], fminf(dj[0], dk[kk]), T[kk]);
                if (1 < wv) T[kk] = fmaf(aj[1], fminf(dj[1], dk[kk]), T[kk]);
                if (2 < wv) T[kk] = fmaf(aj[2], fminf(dj[2], dk[kk]), T[kk]);
            }
        }
    }
    float S = 0.f;
#pragma unroll
    for (int kk = 0; kk < 16; kk++) S = fmaf(ak[kk], T[kk], S);
    {
        float* p = &sPart[(wv * 64 + lane) * 3];
        p[0] = v0; p[1] = v1; p[2] = S;
    }
    __syncthreads();

    // ---- combine + greedy selection (wave 0) ----
    if (t < 64) {
        int k = lane;
        float c0 = 0.f, c1 = 0.f, c2 = 0.f;
#pragma unroll
        for (int u = 0; u < 4; u++) {
            const float* p = &sPart[(u * 64 + k) * 3];
            c0 += p[0]; c1 += p[1]; c2 += p[2];
        }
        float compk = ((c1 + 2.f * c2) / TWO_PI_F) / c0;
        float sc = 1.0f;
        for (int c = 0; c < 7; c++) {
            float score = compk * sc;
            float mx = score;
            for (int off = 1; off < 64; off <<= 1) mx = fmaxf(mx, __shfl_xor(mx, off));
            unsigned long long bl = __ballot(score == mx);
            int idx = __ffsll(bl) - 1;
            float rowk = sAF[idx * 65 + k];
            float clm = sc * rowk;
            sCLM[c * 65 + k] = clm;
            oCLM[(long)w * 512 + c * 64 + k] = clm;
            if (k == 0) oCLR[(long)w * 7 + c] = (float)idx;
            sc *= (1.0f - rowk);
        }
        sCLM[7 * 65 + k] = sc;
        oCLM[(long)w * 512 + 448 + k] = sc;
        oSCM[(long)w * 64 + k] = sc;
    }
    __syncthreads();

    // ---- phase 3: cluster aggregates + second compactness (2 clusters/wave) ----
    {
        int k = lane;
        for (int cc = 0; cc < 2; cc++) {
            int c = wv + cc * 4;
            float clm = sCLM[c * 65 + k];
            float cd = clm * gD, ca = clm * gA;
            float cm = cd * ca;
            float T3 = 0.f;
            for (int j = 0; j < 64; j++)
                T3 = fmaf(rlane(ca, j), fminf(rlane(cd, j), cd), T3);
            float r0 = cm, r1 = ca, r2c = cm * gX, r3 = cm * gY, r4 = clm;
            float r5 = cm * ca;
            float r6 = ca * T3 - ca * ca * cd;   // 2*S contribution (self removed)
            for (int off = 1; off < 64; off <<= 1) {
                r0 += __shfl_xor(r0, off); r1 += __shfl_xor(r1, off);
                r2c += __shfl_xor(r2c, off); r3 += __shfl_xor(r3, off);
                r4 += __shfl_xor(r4, off); r5 += __shfl_xor(r5, off);
                r6 += __shfl_xor(r6, off);
            }
            float mass = r0, area = r1;
            float qx = r2c / (mass + 1e-8f), qy = r3 / (mass + 1e-8f);
            wCLMM[(long)w * 512 + c * 64 + k] = clm / (r4 + 1e-8f);
            float dx = qx - gX, dy = qy - gY;
            float w0v = cd * gI + cm * (dx * dx + dy * dy);
            for (int off = 1; off < 64; off <<= 1) w0v += __shfl_xor(w0v, off);
            if (k == 0) {
                oCOMP[(long)w * 8 + c] = ((r5 + r6) / TWO_PI_F) / w0v;
                float* og = oGEO + (long)w * 48 + c * 6;
                og[0] = mass / (area + 1e-8f); og[1] = mass; og[2] = area;
                og[3] = w0v; og[4] = qx; og[5] = qy;
            }
        }
    }
}

// ---------------------------------------------------------------------------
// cl_f = t1*sigma + sc*(mu+b2) + bfc + u@W2 + t1@Wvf   (Wvf = Wv@Wfc)
//   u = mm@h1, t1 = mm@_fn. readlane-based GEMVs. grid=2048, block=256.
// v3: NO LDS staging of h1/in_f — stage-1 streams straight from global.
// Waves: 0/1 -> u (ch half 0/1); 2/3 -> t1. Stage2: 0/1 -> W2; 2/3 -> Wvf.
// ---------------------------------------------------------------------------
__global__ __launch_bounds__(256, 4) void final_v3(const float* __restrict__ inF,
                                                   const float* __restrict__ H1,
                                                   const float* __restrict__ CLMM,
                                                   const float* __restrict__ stats1,
                                                   const float* __restrict__ W2,
                                                   const float* __restrict__ b2,
                                                   const float* __restrict__ Wvf,
                                                   const float* __restrict__ bfc,
                                                   float* __restrict__ oCLF)
{
    __shared__ float sU[8 * 129];
    __shared__ float sT[8 * 129];
    __shared__ float sP[8 * 129];
    int t = threadIdx.x, w = blockIdx.x;
    int bidx = w >> 8;
    int wv = t >> 6, lane = t & 63;
    int ch = lane + 64 * (wv & 1);

    float mmL[8];
#pragma unroll
    for (int c = 0; c < 8; c++)
        mmL[c] = CLMM[(long)w * 512 + c * 64 + lane];

    float mu = stats1[(bidx * 4 + (ch >> 5)) * 2];
    float rs = stats1[(bidx * 4 + (ch >> 5)) * 2 + 1];

    // ---- stage 1: K=64 GEMVs straight from global ----
    float acc1[8];
#pragma unroll
    for (int c = 0; c < 8; c++) acc1[c] = 0.f;
    if (wv < 2) {
        const float* src = H1 + (long)w * 8192 + ch;
#pragma unroll 4
        for (int j = 0; j < 64; j++) {
            float f = src[j * 128];
#pragma unroll
            for (int c = 0; c < 8; c++)
                acc1[c] = fmaf(rlane(mmL[c], j), f, acc1[c]);
        }
#pragma unroll
        for (int c = 0; c < 8; c++) sU[c * 129 + ch] = acc1[c];
    } else {
        const float* src = inF + (long)w * 8192 + ch;
#pragma unroll 4
        for (int j = 0; j < 64; j++) {
            float f = (src[j * 128] - mu) * rs;
#pragma unroll
            for (int c = 0; c < 8; c++)
                acc1[c] = fmaf(rlane(mmL[c], j), f, acc1[c]);
        }
#pragma unroll
        for (int c = 0; c < 8; c++) sT[c * 129 + ch] = acc1[c];
    }
    __syncthreads();
    // ---- stage 2: K=128 GEMVs with global weights ----
    float xL0[8], xL1[8];
    {
        const float* s2 = (wv < 2) ? sU : sT;
#pragma unroll
        for (int c = 0; c < 8; c++) {
            xL0[c] = s2[c * 129 + lane];
            xL1[c] = s2[c * 129 + 64 + lane];
        }
    }
    const float* Wm = (wv < 2) ? W2 : Wvf;
    float acc2[8];
#pragma unroll
    for (int c = 0; c < 8; c++) acc2[c] = 0.f;
#pragma unroll 2
    for (int k = 0; k < 64; k++) {
        float wk = Wm[k * 128 + ch];
#pragma unroll
        for (int c = 0; c < 8; c++)
            acc2[c] = fmaf(rlane(xL0[c], k), wk, acc2[c]);
    }
#pragma unroll 2
    for (int k = 0; k < 64; k++) {
        float wk = Wm[(k + 64) * 128 + ch];
#pragma unroll
        for (int c = 0; c < 8; c++)
            acc2[c] = fmaf(rlane(xL1[c], k), wk, acc2[c]);
    }
    if (wv >= 2) {
        // + t1 * sigma  (t1[c][ch] is this lane's own value)
        float sig = 1.0f / rs;
#pragma unroll
        for (int c = 0; c < 8; c++) {
            float t1ch = (wv & 1) ? xL1[c] : xL0[c];
            acc2[c] = fmaf(t1ch, sig, acc2[c]);
        }
#pragma unroll
        for (int c = 0; c < 8; c++) sP[c * 129 + ch] = acc2[c];
    }
    __syncthreads();
    if (wv < 2) {
        float scv[8];
#pragma unroll
        for (int c = 0; c < 8; c++) {
            float s = mmL[c];
            for (int off = 1; off < 64; off <<= 1) s += __shfl_xor(s, off);
            scv[c] = s;
        }
        float mub = mu + b2[ch];
        float bfv = bfc[ch];
#pragma unroll
        for (int c = 0; c < 8; c++) {
            float o = acc2[c] + sP[c * 129 + ch] + scv[c] * mub + bfv;
            oCLF[(long)w * 1024 + c * 128 + ch] = o;
        }
    }
}

// ---------------------------------------------------------------------------
extern "C" void kernel_launch(void* const* d_in, const int* in_sizes, int n_in,
                              void* d_out, int out_size, void* d_ws, size_t ws_size,
                              hipStream_t stream)
{
    (void)in_sizes; (void)n_in; (void)out_size; (void)ws_size;
    const float* in_f   = (const float*)d_in[0];
    const float* in_geo = (const float*)d_in[1];
    const float* W1  = (const float*)d_in[2];
    const float* b1  = (const float*)d_in[3];
    const float* W2  = (const float*)d_in[4];
    const float* b2  = (const float*)d_in[5];
    const float* Wfc = (const float*)d_in[6];
    const float* bfc = (const float*)d_in[7];
    const float* Wq  = (const float*)d_in[8];
    const float* Wv  = (const float*)d_in[9];
    float* out = (float*)d_out;
    float* ws  = (float*)d_ws;

    // workspace (floats)
    float* qh     = ws;                    // 16,777,216 (h1)
    float* clmm   = ws + 16777216;         //  1,048,576
    float* stats1 = ws + 17825792;         //  64
    float* stats2 = ws + 17825856;         //  64
    float* wvf    = ws + 17825920;         //  16,384
    float* part   = ws + 17842304;         //  8,192

    // output layout (floats)
    float* o_clf  = out;                   // (8,256,8,128)
    float* o_clm  = out + 2097152;         // (8,256,8,64)
    float* o_geo  = out + 3145728;         // (8,256,8,6)
    float* o_clr  = out + 3244032;         // (8,256,7,1)
    float* o_comp = out + 3258368;         // (8,256,8,1)
    float* o_af   = out + 3274752;         // (8,256,64,64)
    float* o_scm  = out + 11663360;        // (8,256,1,64)
    float* o_q    = out + 11794432;        // (8,256,64,128)

    gn_partial_k<<<dim3(64, 32), 256, 0, stream>>>(in_f, part);
    gn_final_k<<<32, 64, 0, stream>>>(part, stats1, 64);
    wvf_prep_k<<<32, 256, 0, stream>>>(Wv, Wfc, wvf);
    // h1 = leaky(gn1(in_f)@W1 + b1) -> qh;  qraw = gn1(in_f)@Wq -> o_q (+stats2 partials)
    gemm256_fused<<<1024, 256, 0, stream>>>(in_f, W1, b1, Wq, stats1, qh, o_q, part);
    gn_final_k<<<32, 64, 0, stream>>>(part, stats2, 128);
    // attn normalizes qraw IN PLACE in o_q and emits af
    attn_v2<<<1024, 256, 0, stream>>>(o_q, stats2, o_q, o_af);
    cluster_v3<<<2048, 256, 0, stream>>>(o_af, in_geo, o_clm, o_clr, o_comp, o_geo,
                                         o_scm, clmm);
    final_v3<<<2048, 256, 0, stream>>>(in_f, qh, clmm, stats1, W2, b2, wvf, bfc, o_clf);
}

// Round 4
// 467.026 us; speedup vs baseline: 1.0385x; 1.0385x over previous
//
#include <hip/hip_runtime.h>

#define TWO_PI_F 6.28318530717958647692f
#define SCL_F    0.02209708691207961f   // TEMP/SCALE/sqrt(128)

__device__ __forceinline__ float rlane(float v, int l) {
    return __uint_as_float((unsigned)__builtin_amdgcn_readlane((int)__float_as_uint(v), l));
}

// ---------------------------------------------------------------------------
// Group-norm partial stats for in_f: per (b,g) over 16384 rows x 32 ch.
// grid=(64,32), block=256
// ---------------------------------------------------------------------------
__global__ __launch_bounds__(256) void gn_partial_k(const float* __restrict__ X,
                                                    float* __restrict__ partials)
{
    int t = threadIdx.x;
    int chunk = blockIdx.x;
    int grp = blockIdx.y;          // b*4+g
    int b = grp >> 2, g = grp & 3;
    const float* base = X + ((long)b * 16384 + (long)chunk * 256) * 128 + g * 32;
    float s = 0.f, ss = 0.f;
#pragma unroll
    for (int i = 0; i < 8; i++) {
        int rl_ = i * 32 + (t >> 3);
        int c4 = (t & 7) * 4;
        float4 v = *(const float4*)(base + (long)rl_ * 128 + c4);
        s  += v.x + v.y + v.z + v.w;
        ss += v.x * v.x + v.y * v.y + v.z * v.z + v.w * v.w;
    }
    __shared__ float r0[256], r1[256];
    r0[t] = s; r1[t] = ss;
    __syncthreads();
    for (int off = 128; off > 0; off >>= 1) {
        if (t < off) { r0[t] += r0[t + off]; r1[t] += r1[t + off]; }
        __syncthreads();
    }
    if (t == 0) {
        partials[(grp * 64 + chunk) * 2]     = r0[0];
        partials[(grp * 64 + chunk) * 2 + 1] = r1[0];
    }
}

// grid=32, block=64; nblk partials per group
__global__ void gn_final_k(const float* __restrict__ partials, float* __restrict__ stats,
                           int nblk)
{
    int grp = blockIdx.x, t = threadIdx.x;
    float s = 0.f, ss = 0.f;
    for (int i = t; i < nblk; i += 64) {
        s  += partials[(grp * nblk + i) * 2];
        ss += partials[(grp * nblk + i) * 2 + 1];
    }
    for (int off = 1; off < 64; off <<= 1) { s += __shfl_xor(s, off); ss += __shfl_xor(ss, off); }
    if (t == 0) {
        const float N = 524288.0f;
        float mu = s / N;
        float var = ss / N - mu * mu;
        stats[grp * 2]     = mu;
        stats[grp * 2 + 1] = 1.0f / sqrtf(var + 0.001f);
    }
}

// ---------------------------------------------------------------------------
// Wvf = Wv @ Wfc  (128x128). grid=32 blocks x 256 threads (4 rows/block).
// ---------------------------------------------------------------------------
__global__ __launch_bounds__(256) void wvf_prep_k(const float* __restrict__ Wv,
                                                  const float* __restrict__ Wfc,
                                                  float* __restrict__ out)
{
    int t = threadIdx.x;
    int rr = t >> 6, cl = t & 63;
    int r = blockIdx.x * 4 + rr;
    float a0 = 0.f, a1 = 0.f;
    for (int k = 0; k < 128; k++) {
        float wv = Wv[r * 128 + k];
        a0 = fmaf(wv, Wfc[k * 128 + cl], a0);
        a1 = fmaf(wv, Wfc[k * 128 + 64 + cl], a1);
    }
    out[r * 128 + cl] = a0;
    out[r * 128 + 64 + cl] = a1;
}

// ---------------------------------------------------------------------------
// Fused dual GEMM: A = gn1(in_f) tile staged ONCE; waves 0/1 compute
// C1 = leaky(A@W1 + b1) -> h1; waves 2/3 compute C2 = A@Wq -> qraw (+ fused
// stats2 partials from acc). grid=1024 (128 rows/block), block=256.
// sRed aliased onto sA (dead after the K-loop) -> LDS 50,688 B, which fits
// 3 blocks/CU (3*50,688 = 152,064 <= 163,840).
// launch_bounds kept at (256,2): (256,3) caps VGPR at 170 and the compiler
// dropped to 84 < the 128-reg accumulator -> scratch spills (R3 post-mortem:
// WRITE_SIZE +21MB, FETCH +7GB, dur 120->130us). At (256,2) the compiler
// uses 120 VGPR (no spill) and 3*120=360 <= 512/SIMD-lane, so the HW still
// co-schedules 3 blocks/CU; LDS is the binding limit, not the bound arg.
// ---------------------------------------------------------------------------
__global__ __launch_bounds__(256, 2) void gemm256_fused(const float* __restrict__ X,
                                                        const float* __restrict__ W1,
                                                        const float* __restrict__ b1,
                                                        const float* __restrict__ Wq,
                                                        const float* __restrict__ stats,
                                                        float* __restrict__ C1,
                                                        float* __restrict__ C2,
                                                        float* __restrict__ statsout)
{
    __shared__ float sA[32 * 132];
    __shared__ float sB[2][32 * 132];
    float* sRed = sA;                // alias: sA is dead after the K-loop
    int t = threadIdx.x;
    int hw = t >> 7, ht = t & 127;   // hw: 0 -> W1 path, 1 -> Wq path
    long row0 = (long)blockIdx.x * 128;
    int bidx = (int)(row0 >> 14);

    float muv[4], rsv[4];
#pragma unroll
    for (int g = 0; g < 4; g++) {
        muv[g] = stats[(bidx * 4 + g) * 2];
        rsv[g] = stats[(bidx * 4 + g) * 2 + 1];
    }
    int rg = ht >> 3, cg = ht & 7;
    float acc[8][16];
#pragma unroll
    for (int i = 0; i < 8; i++)
#pragma unroll
        for (int j = 0; j < 16; j++) acc[i][j] = 0.f;

    const float* xs = X + (row0 + ht) * 128;
    int kb = ht >> 2, c0 = (ht & 3) * 32;

    for (int kt = 0; kt < 4; kt++) {
        if (hw == 0) {
            // stage A transposed + normalized (k-range [32kt,32kt+32) == group kt)
            float mu = muv[kt], rs = rsv[kt];
            const float* asrc = xs + kt * 32;
#pragma unroll
            for (int q = 0; q < 8; q++) {
                float4 v = *(const float4*)(asrc + 4 * q);
                sA[(4 * q + 0) * 132 + ht] = (v.x - mu) * rs;
                sA[(4 * q + 1) * 132 + ht] = (v.y - mu) * rs;
                sA[(4 * q + 2) * 132 + ht] = (v.z - mu) * rs;
                sA[(4 * q + 3) * 132 + ht] = (v.w - mu) * rs;
            }
        } else {
            // stage both B tiles
            const float* bsrc1 = W1 + (long)(kt * 32 + kb) * 128 + c0;
            const float* bsrc2 = Wq + (long)(kt * 32 + kb) * 128 + c0;
#pragma unroll
            for (int q = 0; q < 8; q++)
                *(float4*)&sB[0][kb * 132 + c0 + 4 * q] = *(const float4*)(bsrc1 + 4 * q);
#pragma unroll
            for (int q = 0; q < 8; q++)
                *(float4*)&sB[1][kb * 132 + c0 + 4 * q] = *(const float4*)(bsrc2 + 4 * q);
        }
        __syncthreads();
        const float* sBh = sB[hw];
#pragma unroll 4
        for (int k = 0; k < 32; k++) {
            float4 a0 = *(const float4*)&sA[k * 132 + rg * 8];
            float4 a1 = *(const float4*)&sA[k * 132 + rg * 8 + 4];
            float b[16];
#pragma unroll
            for (int m = 0; m < 4; m++) {
                float4 bv = *(const float4*)&sBh[k * 132 + cg * 4 + 32 * m];
                b[m * 4 + 0] = bv.x; b[m * 4 + 1] = bv.y;
                b[m * 4 + 2] = bv.z; b[m * 4 + 3] = bv.w;
            }
            float a[8] = {a0.x, a0.y, a0.z, a0.w, a1.x, a1.y, a1.z, a1.w};
#pragma unroll
            for (int i = 0; i < 8; i++)
#pragma unroll
                for (int j = 0; j < 16; j++)
                    acc[i][j] = fmaf(a[i], b[j], acc[i][j]);
        }
        __syncthreads();
    }

    float bv16[16];
#pragma unroll
    for (int m = 0; m < 4; m++)
#pragma unroll
        for (int j = 0; j < 4; j++)
            bv16[m * 4 + j] = (hw == 0) ? b1[cg * 4 + 32 * m + j] : 0.f;
    float* C = hw ? C2 : C1;
#pragma unroll
    for (int i = 0; i < 8; i++) {
        long r = row0 + rg * 8 + i;
#pragma unroll
        for (int m = 0; m < 4; m++) {
            float4 o;
            o.x = acc[i][m * 4 + 0] + bv16[m * 4 + 0];
            o.y = acc[i][m * 4 + 1] + bv16[m * 4 + 1];
            o.z = acc[i][m * 4 + 2] + bv16[m * 4 + 2];
            o.w = acc[i][m * 4 + 3] + bv16[m * 4 + 3];
            if (hw == 0) {
                o.x = (o.x >= 0.f) ? o.x : 0.01f * o.x;
                o.y = (o.y >= 0.f) ? o.y : 0.01f * o.y;
                o.z = (o.z >= 0.f) ? o.z : 0.01f * o.z;
                o.w = (o.w >= 0.f) ? o.w : 0.01f * o.w;
            }
            *(float4*)(C + r * 128 + cg * 4 + 32 * m) = o;
        }
    }
    // fused gn2 partial stats from the Wq half (stored value == acc there)
    if (hw == 1) {
        float s[4] = {0.f, 0.f, 0.f, 0.f}, ss[4] = {0.f, 0.f, 0.f, 0.f};
#pragma unroll
        for (int i = 0; i < 8; i++)
#pragma unroll
            for (int m = 0; m < 4; m++)
#pragma unroll
                for (int j = 0; j < 4; j++) {
                    float v = acc[i][m * 4 + j];
                    s[m] += v; ss[m] += v * v;
                }
#pragma unroll
        for (int m = 0; m < 4; m++) {
            sRed[ht * 8 + 2 * m]     = s[m];
            sRed[ht * 8 + 2 * m + 1] = ss[m];
        }
    }
    __syncthreads();
    if (hw == 1 && ht < 8) {
        int g = ht >> 1, which = ht & 1;
        float a2 = 0.f;
        for (int u = 0; u < 128; u++) a2 += sRed[u * 8 + 2 * g + which];
        statsout[((bidx * 4 + g) * 128 + (int)(blockIdx.x & 127)) * 2 + which] = a2;
    }
}

// ---------------------------------------------------------------------------
// attn: q = gn2(qraw) -> outQ; S = sq_dist(q,q); softmax; min-max -> af
// grid=1024 (2 windows/block), block=256 (128 threads/window, 8x4 tiles).
// sQ XOR-swizzled for conflict-free b128; S aliased into sQ after QK.
// Safe to run IN PLACE (Qraw == outQ): each float4 is read then written by
// the same thread.
// ---------------------------------------------------------------------------
__global__ __launch_bounds__(256, 2) void attn_v2(const float* __restrict__ Qraw,
                                                  const float* __restrict__ stats,
                                                  float* __restrict__ outQ,
                                                  float* __restrict__ outAF)
{
    __shared__ float sQ[2][8192];
    __shared__ float sN[2][64];
    int t = threadIdx.x;
    int wl = t >> 7;               // window half
    int tl = t & 127;
    int w = blockIdx.x * 2 + wl;
    int bidx = w >> 8;
    float muv[4], rsv[4];
#pragma unroll
    for (int g = 0; g < 4; g++) {
        muv[g] = stats[(bidx * 4 + g) * 2];
        rsv[g] = stats[(bidx * 4 + g) * 2 + 1];
    }
    // stage (normalize, write q out, swizzled LDS write)
    {
        int r = tl >> 1, q0 = (tl & 1) * 16;
        int sw = r >> 3;
        const float* src = Qraw + (long)w * 8192 + r * 128 + q0 * 4;
        float* dstG = outQ + (long)w * 8192 + r * 128 + q0 * 4;
#pragma unroll
        for (int q = 0; q < 16; q++) {
            float4 v = *(const float4*)(src + 4 * q);
            int g = (q0 + q) >> 3;
            float mu = muv[g], rs = rsv[g];
            v.x = (v.x - mu) * rs; v.y = (v.y - mu) * rs;
            v.z = (v.z - mu) * rs; v.w = (v.w - mu) * rs;
            *(float4*)(dstG + 4 * q) = v;
            *(float4*)&sQ[wl][r * 128 + 4 * ((q0 + q) ^ sw)] = v;
        }
    }
    __syncthreads();
    if (tl < 64) {
        int r = tl, sw = r >> 3;
        float s = 0.f;
#pragma unroll
        for (int q = 0; q < 32; q++) {
            float4 v = *(const float4*)&sQ[wl][r * 128 + 4 * (q ^ sw)];
            s += v.x * v.x + v.y * v.y + v.z * v.z + v.w * v.w;
        }
        sN[wl][r] = s;
    }
    __syncthreads();
    // QK: rows ty*8+i, cols tx*4+bb
    int ty = tl >> 4, tx = tl & 15;
    float acc[8][4];
#pragma unroll
    for (int i = 0; i < 8; i++)
#pragma unroll
        for (int bb = 0; bb < 4; bb++) acc[i][bb] = 0.f;
    for (int kq = 0; kq < 32; kq++) {
        float4 bf[4];
#pragma unroll
        for (int bb = 0; bb < 4; bb++) {
            int col = tx * 4 + bb;
            bf[bb] = *(const float4*)&sQ[wl][col * 128 + 4 * (kq ^ (col >> 3))];
        }
#pragma unroll
        for (int i = 0; i < 8; i++) {
            int row = ty * 8 + i;
            float4 av = *(const float4*)&sQ[wl][row * 128 + 4 * (kq ^ (row >> 3))];
#pragma unroll
            for (int bb = 0; bb < 4; bb++)
                acc[i][bb] += av.x * bf[bb].x + av.y * bf[bb].y
                            + av.z * bf[bb].z + av.w * bf[bb].w;
        }
    }
    __syncthreads();                 // done reading sQ
    float* sS = &sQ[wl][0];          // alias, stride 65
#pragma unroll
    for (int i = 0; i < 8; i++) {
        int row = ty * 8 + i;
#pragma unroll
        for (int bb = 0; bb < 4; bb++) {
            int col = tx * 4 + bb;
            sS[row * 65 + col] = sN[wl][row] + sN[wl][col] - 2.f * acc[i][bb];
        }
    }
    __syncthreads();
    // epilogue: lane = row, serial over j (no shuffles)
    if (tl < 64) {
        int r = tl;
        float mnS = sS[r * 65];
        for (int j = 1; j < 64; j++) mnS = fminf(mnS, sS[r * 65 + j]);
        float sum = 0.f, pmx = -1.f, pmn = 1e30f;
        for (int j = 0; j < 64; j++) {
            float p = expf(-SCL_F * (sS[r * 65 + j] - mnS));
            sS[r * 65 + j] = p;
            sum += p;
            pmx = fmaxf(pmx, p);
            pmn = fminf(pmn, p);
        }
        float rsum = 1.0f / sum;
        float amn = pmn * rsum, amx = pmx * rsum;
        float dinv = 1.0f / (amx - amn + 1e-8f);
        float* dst = outAF + (long)w * 4096 + r * 64;
        for (int j = 0; j < 64; j += 4) {
            float4 o;
            o.x = (sS[r * 65 + j + 0] * rsum - amn) * dinv;
            o.y = (sS[r * 65 + j + 1] * rsum - amn) * dinv;
            o.z = (sS[r * 65 + j + 2] * rsum - amn) * dinv;
            o.w = (sS[r * 65 + j + 3] * rsum - amn) * dinv;
            *(float4*)(dst + j) = o;
        }
    }
}

// ---------------------------------------------------------------------------
// Per-window clustering, register/readlane rewrite (DS-minimized).
// lane = row q; wave wv owns k = 4kk+wv (registers dk,ak,T[16]).
// Pair sum via min-identity; j<k handled by quad decomposition with
// wave-uniform branches. grid=2048, block=256.
// ---------------------------------------------------------------------------
__global__ __launch_bounds__(256, 4) void cluster_v3(const float* __restrict__ AF,
                                                     const float* __restrict__ GEO,
                                                     float* __restrict__ oCLM,
                                                     float* __restrict__ oCLR,
                                                     float* __restrict__ oCOMP,
                                                     float* __restrict__ oGEO,
                                                     float* __restrict__ oSCM,
                                                     float* __restrict__ wCLMM)
{
    __shared__ float sAF[64 * 65];
    __shared__ float sPart[4 * 64 * 3];
    __shared__ float sCLM[8 * 65];
    int t = threadIdx.x, w = blockIdx.x;
    int wv = t >> 6, lane = t & 63;
    const float* afw = AF + (long)w * 4096;
#pragma unroll
    for (int i = 0; i < 4; i++) {
        int f4 = i * 256 + t;
        float4 v = *(const float4*)(afw + f4 * 4);
        int r = f4 >> 4, c4 = (f4 & 15) * 4;
        float* dst = &sAF[r * 65 + c4];
        dst[0] = fminf(fmaxf(v.x, 1e-5f), 0.99999f);
        dst[1] = fminf(fmaxf(v.y, 1e-5f), 0.99999f);
        dst[2] = fminf(fmaxf(v.z, 1e-5f), 0.99999f);
        dst[3] = fminf(fmaxf(v.w, 1e-5f), 0.99999f);
    }
    // per-lane geo row (lane = element index)
    const float* gp = GEO + ((long)w * 64 + lane) * 6;
    float2 g01 = *(const float2*)(gp);
    float2 g23 = *(const float2*)(gp + 2);
    float2 g45 = *(const float2*)(gp + 4);
    float gD = g01.x, gA = g23.x, gI = g23.y, gX = g45.x, gY = g45.y;
    __syncthreads();

    // ---- phase 1 ----
    const float* afrow = &sAF[lane * 65];
    float dk[16], ak[16], T[16];
    float v0 = 0.f, v1 = 0.f;
#pragma unroll
    for (int kk = 0; kk < 16; kk++) {
        int kc = kk * 4 + wv;
        float afk = afrow[kc];
        float d = afk * rlane(gD, kc);
        float a = afk * rlane(gA, kc);
        dk[kk] = d; ak[kk] = a; T[kk] = 0.f;
        float m = d * a;
        float dx = gX - rlane(gX, kc), dy = gY - rlane(gY, kc);
        v0 += d * rlane(gI, kc) + m * (dx * dx + dy * dy);
        v1 += m * a;
    }
    for (int jq = 0; jq < 16; jq++) {
        float dj[4], aj[4];
#pragma unroll
        for (int jr = 0; jr < 4; jr++) {
            int j = jq * 4 + jr;
            float afj = afrow[j];
            dj[jr] = afj * rlane(gD, j);
            aj[jr] = afj * rlane(gA, j);
        }
#pragma unroll
        for (int kk = 0; kk < 16; kk++) {
            if (kk > jq) {
#pragma unroll
                for (int jr = 0; jr < 4; jr++)
                    T[kk] = fmaf(aj[jr], fminf(dj[jr], dk[kk]), T[kk]);
            } else if (kk == jq) {
                if (0 < wv) T[kk] = fmaf(aj[0], fminf(dj[0], dk[kk]), T[kk]);
                if (1 < wv) T[kk] = fmaf(aj[1], fminf(dj[1], dk[kk]), T[kk]);
                if (2 < wv) T[kk] = fmaf(aj[2], fminf(dj[2], dk[kk]), T[kk]);
            }
        }
    }
    float S = 0.f;
#pragma unroll
    for (int kk = 0; kk < 16; kk++) S = fmaf(ak[kk], T[kk], S);
    {
        float* p = &sPart[(wv * 64 + lane) * 3];
        p[0] = v0; p[1] = v1; p[2] = S;
    }
    __syncthreads();

    // ---- combine + greedy selection (wave 0) ----
    if (t < 64) {
        int k = lane;
        float c0 = 0.f, c1 = 0.f, c2 = 0.f;
#pragma unroll
        for (int u = 0; u < 4; u++) {
            const float* p = &sPart[(u * 64 + k) * 3];
            c0 += p[0]; c1 += p[1]; c2 += p[2];
        }
        float compk = ((c1 + 2.f * c2) / TWO_PI_F) / c0;
        float sc = 1.0f;
        for (int c = 0; c < 7; c++) {
            float score = compk * sc;
            float mx = score;
            for (int off = 1; off < 64; off <<= 1) mx = fmaxf(mx, __shfl_xor(mx, off));
            unsigned long long bl = __ballot(score == mx);
            int idx = __ffsll(bl) - 1;
            float rowk = sAF[idx * 65 + k];
            float clm = sc * rowk;
            sCLM[c * 65 + k] = clm;
            oCLM[(long)w * 512 + c * 64 + k] = clm;
            if (k == 0) oCLR[(long)w * 7 + c] = (float)idx;
            sc *= (1.0f - rowk);
        }
        sCLM[7 * 65 + k] = sc;
        oCLM[(long)w * 512 + 448 + k] = sc;
        oSCM[(long)w * 64 + k] = sc;
    }
    __syncthreads();

    // ---- phase 3: cluster aggregates + second compactness (2 clusters/wave) ----
    {
        int k = lane;
        for (int cc = 0; cc < 2; cc++) {
            int c = wv + cc * 4;
            float clm = sCLM[c * 65 + k];
            float cd = clm * gD, ca = clm * gA;
            float cm = cd * ca;
            float T3 = 0.f;
            for (int j = 0; j < 64; j++)
                T3 = fmaf(rlane(ca, j), fminf(rlane(cd, j), cd), T3);
            float r0 = cm, r1 = ca, r2c = cm * gX, r3 = cm * gY, r4 = clm;
            float r5 = cm * ca;
            float r6 = ca * T3 - ca * ca * cd;   // 2*S contribution (self removed)
            for (int off = 1; off < 64; off <<= 1) {
                r0 += __shfl_xor(r0, off); r1 += __shfl_xor(r1, off);
                r2c += __shfl_xor(r2c, off); r3 += __shfl_xor(r3, off);
                r4 += __shfl_xor(r4, off); r5 += __shfl_xor(r5, off);
                r6 += __shfl_xor(r6, off);
            }
            float mass = r0, area = r1;
            float qx = r2c / (mass + 1e-8f), qy = r3 / (mass + 1e-8f);
            wCLMM[(long)w * 512 + c * 64 + k] = clm / (r4 + 1e-8f);
            float dx = qx - gX, dy = qy - gY;
            float w0v = cd * gI + cm * (dx * dx + dy * dy);
            for (int off = 1; off < 64; off <<= 1) w0v += __shfl_xor(w0v, off);
            if (k == 0) {
                oCOMP[(long)w * 8 + c] = ((r5 + r6) / TWO_PI_F) / w0v;
                float* og = oGEO + (long)w * 48 + c * 6;
                og[0] = mass / (area + 1e-8f); og[1] = mass; og[2] = area;
                og[3] = w0v; og[4] = qx; og[5] = qy;
            }
        }
    }
}

// ---------------------------------------------------------------------------
// cl_f = t1*sigma + sc*(mu+b2) + bfc + u@W2 + t1@Wvf   (Wvf = Wv@Wfc)
//   u = mm@h1, t1 = mm@_fn. readlane-based GEMVs. grid=2048, block=256.
// v3: NO LDS staging of h1/in_f — stage-1 streams straight from global.
// Waves: 0/1 -> u (ch half 0/1); 2/3 -> t1. Stage2: 0/1 -> W2; 2/3 -> Wvf.
// ---------------------------------------------------------------------------
__global__ __launch_bounds__(256, 4) void final_v3(const float* __restrict__ inF,
                                                   const float* __restrict__ H1,
                                                   const float* __restrict__ CLMM,
                                                   const float* __restrict__ stats1,
                                                   const float* __restrict__ W2,
                                                   const float* __restrict__ b2,
                                                   const float* __restrict__ Wvf,
                                                   const float* __restrict__ bfc,
                                                   float* __restrict__ oCLF)
{
    __shared__ float sU[8 * 129];
    __shared__ float sT[8 * 129];
    __shared__ float sP[8 * 129];
    int t = threadIdx.x, w = blockIdx.x;
    int bidx = w >> 8;
    int wv = t >> 6, lane = t & 63;
    int ch = lane + 64 * (wv & 1);

    float mmL[8];
#pragma unroll
    for (int c = 0; c < 8; c++)
        mmL[c] = CLMM[(long)w * 512 + c * 64 + lane];

    float mu = stats1[(bidx * 4 + (ch >> 5)) * 2];
    float rs = stats1[(bidx * 4 + (ch >> 5)) * 2 + 1];

    // ---- stage 1: K=64 GEMVs straight from global ----
    float acc1[8];
#pragma unroll
    for (int c = 0; c < 8; c++) acc1[c] = 0.f;
    if (wv < 2) {
        const float* src = H1 + (long)w * 8192 + ch;
#pragma unroll 4
        for (int j = 0; j < 64; j++) {
            float f = src[j * 128];
#pragma unroll
            for (int c = 0; c < 8; c++)
                acc1[c] = fmaf(rlane(mmL[c], j), f, acc1[c]);
        }
#pragma unroll
        for (int c = 0; c < 8; c++) sU[c * 129 + ch] = acc1[c];
    } else {
        const float* src = inF + (long)w * 8192 + ch;
#pragma unroll 4
        for (int j = 0; j < 64; j++) {
            float f = (src[j * 128] - mu) * rs;
#pragma unroll
            for (int c = 0; c < 8; c++)
                acc1[c] = fmaf(rlane(mmL[c], j), f, acc1[c]);
        }
#pragma unroll
        for (int c = 0; c < 8; c++) sT[c * 129 + ch] = acc1[c];
    }
    __syncthreads();
    // ---- stage 2: K=128 GEMVs with global weights ----
    float xL0[8], xL1[8];
    {
        const float* s2 = (wv < 2) ? sU : sT;
#pragma unroll
        for (int c = 0; c < 8; c++) {
            xL0[c] = s2[c * 129 + lane];
            xL1[c] = s2[c * 129 + 64 + lane];
        }
    }
    const float* Wm = (wv < 2) ? W2 : Wvf;
    float acc2[8];
#pragma unroll
    for (int c = 0; c < 8; c++) acc2[c] = 0.f;
#pragma unroll 2
    for (int k = 0; k < 64; k++) {
        float wk = Wm[k * 128 + ch];
#pragma unroll
        for (int c = 0; c < 8; c++)
            acc2[c] = fmaf(rlane(xL0[c], k), wk, acc2[c]);
    }
#pragma unroll 2
    for (int k = 0; k < 64; k++) {
        float wk = Wm[(k + 64) * 128 + ch];
#pragma unroll
        for (int c = 0; c < 8; c++)
            acc2[c] = fmaf(rlane(xL1[c], k), wk, acc2[c]);
    }
    if (wv >= 2) {
        // + t1 * sigma  (t1[c][ch] is this lane's own value)
        float sig = 1.0f / rs;
#pragma unroll
        for (int c = 0; c < 8; c++) {
            float t1ch = (wv & 1) ? xL1[c] : xL0[c];
            acc2[c] = fmaf(t1ch, sig, acc2[c]);
        }
#pragma unroll
        for (int c = 0; c < 8; c++) sP[c * 129 + ch] = acc2[c];
    }
    __syncthreads();
    if (wv < 2) {
        float scv[8];
#pragma unroll
        for (int c = 0; c < 8; c++) {
            float s = mmL[c];
            for (int off = 1; off < 64; off <<= 1) s += __shfl_xor(s, off);
            scv[c] = s;
        }
        float mub = mu + b2[ch];
        float bfv = bfc[ch];
#pragma unroll
        for (int c = 0; c < 8; c++) {
            float o = acc2[c] + sP[c * 129 + ch] + scv[c] * mub + bfv;
            oCLF[(long)w * 1024 + c * 128 + ch] = o;
        }
    }
}

// ---------------------------------------------------------------------------
extern "C" void kernel_launch(void* const* d_in, const int* in_sizes, int n_in,
                              void* d_out, int out_size, void* d_ws, size_t ws_size,
                              hipStream_t stream)
{
    (void)in_sizes; (void)n_in; (void)out_size; (void)ws_size;
    const float* in_f   = (const float*)d_in[0];
    const float* in_geo = (const float*)d_in[1];
    const float* W1  = (const float*)d_in[2];
    const float* b1  = (const float*)d_in[3];
    const float* W2  = (const float*)d_in[4];
    const float* b2  = (const float*)d_in[5];
    const float* Wfc = (const float*)d_in[6];
    const float* bfc = (const float*)d_in[7];
    const float* Wq  = (const float*)d_in[8];
    const float* Wv  = (const float*)d_in[9];
    float* out = (float*)d_out;
    float* ws  = (float*)d_ws;

    // workspace (floats)
    float* qh     = ws;                    // 16,777,216 (h1)
    float* clmm   = ws + 16777216;         //  1,048,576
    float* stats1 = ws + 17825792;         //  64
    float* stats2 = ws + 17825856;         //  64
    float* wvf    = ws + 17825920;         //  16,384
    float* part   = ws + 17842304;         //  8,192

    // output layout (floats)
    float* o_clf  = out;                   // (8,256,8,128)
    float* o_clm  = out + 2097152;         // (8,256,8,64)
    float* o_geo  = out + 3145728;         // (8,256,8,6)
    float* o_clr  = out + 3244032;         // (8,256,7,1)
    float* o_comp = out + 3258368;         // (8,256,8,1)
    float* o_af   = out + 3274752;         // (8,256,64,64)
    float* o_scm  = out + 11663360;        // (8,256,1,64)
    float* o_q    = out + 11794432;        // (8,256,64,128)

    gn_partial_k<<<dim3(64, 32), 256, 0, stream>>>(in_f, part);
    gn_final_k<<<32, 64, 0, stream>>>(part, stats1, 64);
    wvf_prep_k<<<32, 256, 0, stream>>>(Wv, Wfc, wvf);
    // h1 = leaky(gn1(in_f)@W1 + b1) -> qh;  qraw = gn1(in_f)@Wq -> o_q (+stats2 partials)
    gemm256_fused<<<1024, 256, 0, stream>>>(in_f, W1, b1, Wq, stats1, qh, o_q, part);
    gn_final_k<<<32, 64, 0, stream>>>(part, stats2, 128);
    // attn normalizes qraw IN PLACE in o_q and emits af
    attn_v2<<<1024, 256, 0, stream>>>(o_q, stats2, o_q, o_af);
    cluster_v3<<<2048, 256, 0, stream>>>(o_af, in_geo, o_clm, o_clr, o_comp, o_geo,
                                         o_scm, clmm);
    final_v3<<<2048, 256, 0, stream>>>(in_f, qh, clmm, stats1, W2, b2, wvf, bfc, o_clf);
}

// Round 5
// 394.351 us; speedup vs baseline: 1.2298x; 1.1843x over previous
//
#include <hip/hip_runtime.h>

#define TWO_PI_F 6.28318530717958647692f
#define SCL_F    0.02209708691207961f   // TEMP/SCALE/sqrt(128)

typedef __attribute__((ext_vector_type(8))) short s16x8;
typedef __attribute__((ext_vector_type(4))) float f32x4;

__device__ __forceinline__ float rlane(float v, int l) {
    return __uint_as_float((unsigned)__builtin_amdgcn_readlane((int)__float_as_uint(v), l));
}

__device__ __forceinline__ unsigned short f2bf(float f) {
    unsigned u = __float_as_uint(f);
    return (unsigned short)((u + 0x7fff + ((u >> 16) & 1)) >> 16);
}
__device__ __forceinline__ float bf2f(unsigned short h) {
    return __uint_as_float(((unsigned)h) << 16);
}

// ---------------------------------------------------------------------------
// Group-norm partial stats for in_f: per (b,g) over 16384 rows x 32 ch.
// grid=(64,32), block=256
// ---------------------------------------------------------------------------
__global__ __launch_bounds__(256) void gn_partial_k(const float* __restrict__ X,
                                                    float* __restrict__ partials)
{
    int t = threadIdx.x;
    int chunk = blockIdx.x;
    int grp = blockIdx.y;          // b*4+g
    int b = grp >> 2, g = grp & 3;
    const float* base = X + ((long)b * 16384 + (long)chunk * 256) * 128 + g * 32;
    float s = 0.f, ss = 0.f;
#pragma unroll
    for (int i = 0; i < 8; i++) {
        int rl_ = i * 32 + (t >> 3);
        int c4 = (t & 7) * 4;
        float4 v = *(const float4*)(base + (long)rl_ * 128 + c4);
        s  += v.x + v.y + v.z + v.w;
        ss += v.x * v.x + v.y * v.y + v.z * v.z + v.w * v.w;
    }
    __shared__ float r0[256], r1[256];
    r0[t] = s; r1[t] = ss;
    __syncthreads();
    for (int off = 128; off > 0; off >>= 1) {
        if (t < off) { r0[t] += r0[t + off]; r1[t] += r1[t + off]; }
        __syncthreads();
    }
    if (t == 0) {
        partials[(grp * 64 + chunk) * 2]     = r0[0];
        partials[(grp * 64 + chunk) * 2 + 1] = r1[0];
    }
}

// grid=32, block=64; nblk partials per group
__global__ void gn_final_k(const float* __restrict__ partials, float* __restrict__ stats,
                           int nblk)
{
    int grp = blockIdx.x, t = threadIdx.x;
    float s = 0.f, ss = 0.f;
    for (int i = t; i < nblk; i += 64) {
        s  += partials[(grp * nblk + i) * 2];
        ss += partials[(grp * nblk + i) * 2 + 1];
    }
    for (int off = 1; off < 64; off <<= 1) { s += __shfl_xor(s, off); ss += __shfl_xor(ss, off); }
    if (t == 0) {
        const float N = 524288.0f;
        float mu = s / N;
        float var = ss / N - mu * mu;
        stats[grp * 2]     = mu;
        stats[grp * 2 + 1] = 1.0f / sqrtf(var + 0.001f);
    }
}

// ---------------------------------------------------------------------------
// Wvf = Wv @ Wfc  (128x128). grid=32 blocks x 256 threads (4 rows/block).
// ---------------------------------------------------------------------------
__global__ __launch_bounds__(256) void wvf_prep_k(const float* __restrict__ Wv,
                                                  const float* __restrict__ Wfc,
                                                  float* __restrict__ out)
{
    int t = threadIdx.x;
    int rr = t >> 6, cl = t & 63;
    int r = blockIdx.x * 4 + rr;
    float a0 = 0.f, a1 = 0.f;
    for (int k = 0; k < 128; k++) {
        float wv = Wv[r * 128 + k];
        a0 = fmaf(wv, Wfc[k * 128 + cl], a0);
        a1 = fmaf(wv, Wfc[k * 128 + 64 + cl], a1);
    }
    out[r * 128 + cl] = a0;
    out[r * 128 + 64 + cl] = a1;
}

// ---------------------------------------------------------------------------
// Split Bcat = [W1 | Wq] (stored [k][n] row-major) into bf16 hi/lo planes,
// TRANSPOSED: WT*[col][k], col 0..255 (0-127 = W1 cols, 128-255 = Wq cols).
// grid=128, block=256.
// ---------------------------------------------------------------------------
__global__ __launch_bounds__(256) void wsplit_prep_k(const float* __restrict__ W1,
                                                     const float* __restrict__ Wq,
                                                     unsigned short* __restrict__ WThi,
                                                     unsigned short* __restrict__ WTlo)
{
    int idx = blockIdx.x * 256 + threadIdx.x;   // 32768 total
    int col = idx >> 7, k = idx & 127;
    float w = (col < 128) ? W1[k * 128 + col] : Wq[k * 128 + (col - 128)];
    unsigned short hb = f2bf(w);
    float hf = bf2f(hb);
    WThi[col * 128 + k] = hb;
    WTlo[col * 128 + k] = f2bf(w - hf);
}

// ---------------------------------------------------------------------------
// MFMA dual GEMM via bf16 hi/lo split: C = gn1(X) @ [W1|Wq] with
//   C ~= Ahi@Bhi + Alo@Bhi + Ahi@Blo   (error ~1e-5 rel, near-fp32).
// grid=1024 (128 rows/block), block=512 (8 waves).
// Waves 0-3: W1 half (leaky+bias -> C1); waves 4-7: Wq half (-> C2 + stats).
// Wave wv&3 owns rows (wv&3)*32..+31 (2 Mtiles) x 8 Ntiles; acc = 16 f32x4.
// K-loop: 4 chunks of 32 (aligned with gn groups). A staged+normalized+split
// to LDS bf16; B slices copied from pre-split global planes.
// MFMA fragment mapping (guide-verified): row/col = lane&15,
// k = (lane>>4)*8 + j (contiguous; any within-chunk k-permutation cancels
// since A and B frags are loaded identically); D: col=lane&15,
// row=(lane>>4)*4+reg.
// LDS = 61,440 B -> 2 blocks/CU = 16 waves/CU; VGPR budget ~115 < 128.
// ---------------------------------------------------------------------------
__global__ __launch_bounds__(512, 4) void gemm_mfma_dual(const float* __restrict__ X,
                                                         const unsigned short* __restrict__ WThi,
                                                         const unsigned short* __restrict__ WTlo,
                                                         const float* __restrict__ b1,
                                                         const float* __restrict__ stats,
                                                         float* __restrict__ C1,
                                                         float* __restrict__ C2,
                                                         float* __restrict__ statsout)
{
    __shared__ short sAhi[128 * 40];   // [row][k] bf16, stride 40 (pad)
    __shared__ short sAlo[128 * 40];
    __shared__ short sBhi[256 * 40];   // [col][k] bf16, stride 40
    __shared__ short sBlo[256 * 40];
    int t = threadIdx.x;
    int wv = t >> 6, lane = t & 63;
    int half = wv >> 2;                // 0 -> W1, 1 -> Wq
    int mrow0 = (wv & 3) * 32;
    long row0 = (long)blockIdx.x * 128;
    int bidx = (int)(row0 >> 14);

    float muv[4], rsv[4];
#pragma unroll
    for (int g = 0; g < 4; g++) {
        muv[g] = stats[(bidx * 4 + g) * 2];
        rsv[g] = stats[(bidx * 4 + g) * 2 + 1];
    }

    f32x4 acc[2][8];
#pragma unroll
    for (int m2 = 0; m2 < 2; m2++)
#pragma unroll
        for (int nt = 0; nt < 8; nt++) acc[m2][nt] = (f32x4){0.f, 0.f, 0.f, 0.f};

    int lr = lane & 15, lk = (lane >> 4) * 8;
    // staging assignments
    int arow = t >> 2, akq = (t & 3) * 8;        // A: 128 rows x 32 k, 8 elems/thr
    int bcol = t >> 1, bko = (t & 1) * 16;       // B: 256 cols x 32 k, 16 elems/thr/plane
    const float* xsrc = X + (row0 + arow) * 128;

    for (int kt = 0; kt < 4; kt++) {
        // ---- stage A (normalize, split hi/lo) ----
        {
            float mu = muv[kt], rs = rsv[kt];
            float4 x0 = *(const float4*)(xsrc + kt * 32 + akq);
            float4 x1 = *(const float4*)(xsrc + kt * 32 + akq + 4);
            float v[8];
            v[0] = x0.x; v[1] = x0.y; v[2] = x0.z; v[3] = x0.w;
            v[4] = x1.x; v[5] = x1.y; v[6] = x1.z; v[7] = x1.w;
            s16x8 vh, vl;
#pragma unroll
            for (int j = 0; j < 8; j++) {
                float x = (v[j] - mu) * rs;
                unsigned short hb = f2bf(x);
                float hf = bf2f(hb);
                unsigned short lb = f2bf(x - hf);
                vh[j] = (short)hb;
                vl[j] = (short)lb;
            }
            *(s16x8*)&sAhi[arow * 40 + akq] = vh;
            *(s16x8*)&sAlo[arow * 40 + akq] = vl;
        }
        // ---- stage B (copy pre-split planes) ----
        {
            const unsigned short* sh = WThi + bcol * 128 + kt * 32 + bko;
            const unsigned short* sl = WTlo + bcol * 128 + kt * 32 + bko;
            *(s16x8*)&sBhi[bcol * 40 + bko]     = *(const s16x8*)(sh);
            *(s16x8*)&sBhi[bcol * 40 + bko + 8] = *(const s16x8*)(sh + 8);
            *(s16x8*)&sBlo[bcol * 40 + bko]     = *(const s16x8*)(sl);
            *(s16x8*)&sBlo[bcol * 40 + bko + 8] = *(const s16x8*)(sl + 8);
        }
        __syncthreads();
        // ---- fragments + MFMA ----
        s16x8 ahi[2], alo[2];
#pragma unroll
        for (int m2 = 0; m2 < 2; m2++) {
            int row = mrow0 + m2 * 16 + lr;
            ahi[m2] = *(const s16x8*)&sAhi[row * 40 + lk];
            alo[m2] = *(const s16x8*)&sAlo[row * 40 + lk];
        }
#pragma unroll
        for (int nt = 0; nt < 8; nt++) {
            int col = half * 128 + nt * 16 + lr;
            s16x8 bhi = *(const s16x8*)&sBhi[col * 40 + lk];
            s16x8 blo = *(const s16x8*)&sBlo[col * 40 + lk];
#pragma unroll
            for (int m2 = 0; m2 < 2; m2++) {
                acc[m2][nt] = __builtin_amdgcn_mfma_f32_16x16x32_bf16(ahi[m2], bhi, acc[m2][nt], 0, 0, 0);
                acc[m2][nt] = __builtin_amdgcn_mfma_f32_16x16x32_bf16(alo[m2], bhi, acc[m2][nt], 0, 0, 0);
                acc[m2][nt] = __builtin_amdgcn_mfma_f32_16x16x32_bf16(ahi[m2], blo, acc[m2][nt], 0, 0, 0);
            }
        }
        __syncthreads();
    }

    // ---- epilogue: bias/leaky + store ----
    int rg4 = (lane >> 4) * 4;
    float* C = half ? C2 : C1;
    float bv[8];
    if (half == 0) {
#pragma unroll
        for (int nt = 0; nt < 8; nt++) bv[nt] = b1[nt * 16 + lr];
    }
#pragma unroll
    for (int m2 = 0; m2 < 2; m2++) {
        long rbase = row0 + mrow0 + m2 * 16 + rg4;
#pragma unroll
        for (int nt = 0; nt < 8; nt++) {
#pragma unroll
            for (int r = 0; r < 4; r++) {
                float v = acc[m2][nt][r];
                if (half == 0) {
                    v += bv[nt];
                    v = (v >= 0.f) ? v : 0.01f * v;
                }
                C[(rbase + r) * 128 + nt * 16 + lr] = v;
            }
        }
    }
    // ---- fused gn2 partial stats from the Wq half ----
    float s4[4] = {0.f, 0.f, 0.f, 0.f}, ss4[4] = {0.f, 0.f, 0.f, 0.f};
    if (half == 1) {
#pragma unroll
        for (int m2 = 0; m2 < 2; m2++)
#pragma unroll
            for (int nt = 0; nt < 8; nt++) {
                int g = nt >> 1;
#pragma unroll
                for (int r = 0; r < 4; r++) {
                    float v = acc[m2][nt][r];
                    s4[g] += v; ss4[g] += v * v;
                }
            }
    }
    __syncthreads();
    float* sRed = (float*)sAhi;   // 8 KB needed <= 10,240 B; sA dead
    if (half == 1) {
        int q = t & 255;
#pragma unroll
        for (int g = 0; g < 4; g++) {
            sRed[q * 8 + 2 * g]     = s4[g];
            sRed[q * 8 + 2 * g + 1] = ss4[g];
        }
    }
    __syncthreads();
    if (t < 8) {
        int g = t >> 1, which = t & 1;
        float a2 = 0.f;
        for (int u = 0; u < 256; u++) a2 += sRed[u * 8 + 2 * g + which];
        statsout[((bidx * 4 + g) * 128 + (int)(blockIdx.x & 127)) * 2 + which] = a2;
    }
}

// ---------------------------------------------------------------------------
// attn: q = gn2(qraw) -> outQ; S = sq_dist(q,q); softmax; min-max -> af
// grid=1024 (2 windows/block), block=256 (128 threads/window, 8x4 tiles).
// sQ XOR-swizzled for conflict-free b128; S aliased into sQ after QK.
// Safe to run IN PLACE (Qraw == outQ).
// ---------------------------------------------------------------------------
__global__ __launch_bounds__(256, 2) void attn_v2(const float* __restrict__ Qraw,
                                                  const float* __restrict__ stats,
                                                  float* __restrict__ outQ,
                                                  float* __restrict__ outAF)
{
    __shared__ float sQ[2][8192];
    __shared__ float sN[2][64];
    int t = threadIdx.x;
    int wl = t >> 7;               // window half
    int tl = t & 127;
    int w = blockIdx.x * 2 + wl;
    int bidx = w >> 8;
    float muv[4], rsv[4];
#pragma unroll
    for (int g = 0; g < 4; g++) {
        muv[g] = stats[(bidx * 4 + g) * 2];
        rsv[g] = stats[(bidx * 4 + g) * 2 + 1];
    }
    // stage (normalize, write q out, swizzled LDS write)
    {
        int r = tl >> 1, q0 = (tl & 1) * 16;
        int sw = r >> 3;
        const float* src = Qraw + (long)w * 8192 + r * 128 + q0 * 4;
        float* dstG = outQ + (long)w * 8192 + r * 128 + q0 * 4;
#pragma unroll
        for (int q = 0; q < 16; q++) {
            float4 v = *(const float4*)(src + 4 * q);
            int g = (q0 + q) >> 3;
            float mu = muv[g], rs = rsv[g];
            v.x = (v.x - mu) * rs; v.y = (v.y - mu) * rs;
            v.z = (v.z - mu) * rs; v.w = (v.w - mu) * rs;
            *(float4*)(dstG + 4 * q) = v;
            *(float4*)&sQ[wl][r * 128 + 4 * ((q0 + q) ^ sw)] = v;
        }
    }
    __syncthreads();
    if (tl < 64) {
        int r = tl, sw = r >> 3;
        float s = 0.f;
#pragma unroll
        for (int q = 0; q < 32; q++) {
            float4 v = *(const float4*)&sQ[wl][r * 128 + 4 * (q ^ sw)];
            s += v.x * v.x + v.y * v.y + v.z * v.z + v.w * v.w;
        }
        sN[wl][r] = s;
    }
    __syncthreads();
    // QK: rows ty*8+i, cols tx*4+bb
    int ty = tl >> 4, tx = tl & 15;
    float acc[8][4];
#pragma unroll
    for (int i = 0; i < 8; i++)
#pragma unroll
        for (int bb = 0; bb < 4; bb++) acc[i][bb] = 0.f;
    for (int kq = 0; kq < 32; kq++) {
        float4 bf[4];
#pragma unroll
        for (int bb = 0; bb < 4; bb++) {
            int col = tx * 4 + bb;
            bf[bb] = *(const float4*)&sQ[wl][col * 128 + 4 * (kq ^ (col >> 3))];
        }
#pragma unroll
        for (int i = 0; i < 8; i++) {
            int row = ty * 8 + i;
            float4 av = *(const float4*)&sQ[wl][row * 128 + 4 * (kq ^ (row >> 3))];
#pragma unroll
            for (int bb = 0; bb < 4; bb++)
                acc[i][bb] += av.x * bf[bb].x + av.y * bf[bb].y
                            + av.z * bf[bb].z + av.w * bf[bb].w;
        }
    }
    __syncthreads();                 // done reading sQ
    float* sS = &sQ[wl][0];          // alias, stride 65
#pragma unroll
    for (int i = 0; i < 8; i++) {
        int row = ty * 8 + i;
#pragma unroll
        for (int bb = 0; bb < 4; bb++) {
            int col = tx * 4 + bb;
            sS[row * 65 + col] = sN[wl][row] + sN[wl][col] - 2.f * acc[i][bb];
        }
    }
    __syncthreads();
    // epilogue: lane = row, serial over j (no shuffles)
    if (tl < 64) {
        int r = tl;
        float mnS = sS[r * 65];
        for (int j = 1; j < 64; j++) mnS = fminf(mnS, sS[r * 65 + j]);
        float sum = 0.f, pmx = -1.f, pmn = 1e30f;
        for (int j = 0; j < 64; j++) {
            float p = expf(-SCL_F * (sS[r * 65 + j] - mnS));
            sS[r * 65 + j] = p;
            sum += p;
            pmx = fmaxf(pmx, p);
            pmn = fminf(pmn, p);
        }
        float rsum = 1.0f / sum;
        float amn = pmn * rsum, amx = pmx * rsum;
        float dinv = 1.0f / (amx - amn + 1e-8f);
        float* dst = outAF + (long)w * 4096 + r * 64;
        for (int j = 0; j < 64; j += 4) {
            float4 o;
            o.x = (sS[r * 65 + j + 0] * rsum - amn) * dinv;
            o.y = (sS[r * 65 + j + 1] * rsum - amn) * dinv;
            o.z = (sS[r * 65 + j + 2] * rsum - amn) * dinv;
            o.w = (sS[r * 65 + j + 3] * rsum - amn) * dinv;
            *(float4*)(dst + j) = o;
        }
    }
}

// ---------------------------------------------------------------------------
// Per-window clustering, register/readlane rewrite (DS-minimized).
// grid=2048, block=256.
// ---------------------------------------------------------------------------
__global__ __launch_bounds__(256, 4) void cluster_v3(const float* __restrict__ AF,
                                                     const float* __restrict__ GEO,
                                                     float* __restrict__ oCLM,
                                                     float* __restrict__ oCLR,
                                                     float* __restrict__ oCOMP,
                                                     float* __restrict__ oGEO,
                                                     float* __restrict__ oSCM,
                                                     float* __restrict__ wCLMM)
{
    __shared__ float sAF[64 * 65];
    __shared__ float sPart[4 * 64 * 3];
    __shared__ float sCLM[8 * 65];
    int t = threadIdx.x, w = blockIdx.x;
    int wv = t >> 6, lane = t & 63;
    const float* afw = AF + (long)w * 4096;
#pragma unroll
    for (int i = 0; i < 4; i++) {
        int f4 = i * 256 + t;
        float4 v = *(const float4*)(afw + f4 * 4);
        int r = f4 >> 4, c4 = (f4 & 15) * 4;
        float* dst = &sAF[r * 65 + c4];
        dst[0] = fminf(fmaxf(v.x, 1e-5f), 0.99999f);
        dst[1] = fminf(fmaxf(v.y, 1e-5f), 0.99999f);
        dst[2] = fminf(fmaxf(v.z, 1e-5f), 0.99999f);
        dst[3] = fminf(fmaxf(v.w, 1e-5f), 0.99999f);
    }
    // per-lane geo row (lane = element index)
    const float* gp = GEO + ((long)w * 64 + lane) * 6;
    float2 g01 = *(const float2*)(gp);
    float2 g23 = *(const float2*)(gp + 2);
    float2 g45 = *(const float2*)(gp + 4);
    float gD = g01.x, gA = g23.x, gI = g23.y, gX = g45.x, gY = g45.y;
    __syncthreads();

    // ---- phase 1 ----
    const float* afrow = &sAF[lane * 65];
    float dk[16], ak[16], T[16];
    float v0 = 0.f, v1 = 0.f;
#pragma unroll
    for (int kk = 0; kk < 16; kk++) {
        int kc = kk * 4 + wv;
        float afk = afrow[kc];
        float d = afk * rlane(gD, kc);
        float a = afk * rlane(gA, kc);
        dk[kk] = d; ak[kk] = a; T[kk] = 0.f;
        float m = d * a;
        float dx = gX - rlane(gX, kc), dy = gY - rlane(gY, kc);
        v0 += d * rlane(gI, kc) + m * (dx * dx + dy * dy);
        v1 += m * a;
    }
    for (int jq = 0; jq < 16; jq++) {
        float dj[4], aj[4];
#pragma unroll
        for (int jr = 0; jr < 4; jr++) {
            int j = jq * 4 + jr;
            float afj = afrow[j];
            dj[jr] = afj * rlane(gD, j);
            aj[jr] = afj * rlane(gA, j);
        }
#pragma unroll
        for (int kk = 0; kk < 16; kk++) {
            if (kk > jq) {
#pragma unroll
                for (int jr = 0; jr < 4; jr++)
                    T[kk] = fmaf(aj[jr], fminf(dj[jr], dk[kk]), T[kk]);
            } else if (kk == jq) {
                if (0 < wv) T[kk] = fmaf(aj[0], fminf(dj[0], dk[kk]), T[kk]);
                if (1 < wv) T[kk] = fmaf(aj[1], fminf(dj[1], dk[kk]), T[kk]);
                if (2 < wv) T[kk] = fmaf(aj[2], fminf(dj[2], dk[kk]), T[kk]);
            }
        }
    }
    float S = 0.f;
#pragma unroll
    for (int kk = 0; kk < 16; kk++) S = fmaf(ak[kk], T[kk], S);
    {
        float* p = &sPart[(wv * 64 + lane) * 3];
        p[0] = v0; p[1] = v1; p[2] = S;
    }
    __syncthreads();

    // ---- combine + greedy selection (wave 0) ----
    if (t < 64) {
        int k = lane;
        float c0 = 0.f, c1 = 0.f, c2 = 0.f;
#pragma unroll
        for (int u = 0; u < 4; u++) {
            const float* p = &sPart[(u * 64 + k) * 3];
            c0 += p[0]; c1 += p[1]; c2 += p[2];
        }
        float compk = ((c1 + 2.f * c2) / TWO_PI_F) / c0;
        float sc = 1.0f;
        for (int c = 0; c < 7; c++) {
            float score = compk * sc;
            float mx = score;
            for (int off = 1; off < 64; off <<= 1) mx = fmaxf(mx, __shfl_xor(mx, off));
            unsigned long long bl = __ballot(score == mx);
            int idx = __ffsll(bl) - 1;
            float rowk = sAF[idx * 65 + k];
            float clm = sc * rowk;
            sCLM[c * 65 + k] = clm;
            oCLM[(long)w * 512 + c * 64 + k] = clm;
            if (k == 0) oCLR[(long)w * 7 + c] = (float)idx;
            sc *= (1.0f - rowk);
        }
        sCLM[7 * 65 + k] = sc;
        oCLM[(long)w * 512 + 448 + k] = sc;
        oSCM[(long)w * 64 + k] = sc;
    }
    __syncthreads();

    // ---- phase 3: cluster aggregates + second compactness (2 clusters/wave) ----
    {
        int k = lane;
        for (int cc = 0; cc < 2; cc++) {
            int c = wv + cc * 4;
            float clm = sCLM[c * 65 + k];
            float cd = clm * gD, ca = clm * gA;
            float cm = cd * ca;
            float T3 = 0.f;
            for (int j = 0; j < 64; j++)
                T3 = fmaf(rlane(ca, j), fminf(rlane(cd, j), cd), T3);
            float r0 = cm, r1 = ca, r2c = cm * gX, r3 = cm * gY, r4 = clm;
            float r5 = cm * ca;
            float r6 = ca * T3 - ca * ca * cd;   // 2*S contribution (self removed)
            for (int off = 1; off < 64; off <<= 1) {
                r0 += __shfl_xor(r0, off); r1 += __shfl_xor(r1, off);
                r2c += __shfl_xor(r2c, off); r3 += __shfl_xor(r3, off);
                r4 += __shfl_xor(r4, off); r5 += __shfl_xor(r5, off);
                r6 += __shfl_xor(r6, off);
            }
            float mass = r0, area = r1;
            float qx = r2c / (mass + 1e-8f), qy = r3 / (mass + 1e-8f);
            wCLMM[(long)w * 512 + c * 64 + k] = clm / (r4 + 1e-8f);
            float dx = qx - gX, dy = qy - gY;
            float w0v = cd * gI + cm * (dx * dx + dy * dy);
            for (int off = 1; off < 64; off <<= 1) w0v += __shfl_xor(w0v, off);
            if (k == 0) {
                oCOMP[(long)w * 8 + c] = ((r5 + r6) / TWO_PI_F) / w0v;
                float* og = oGEO + (long)w * 48 + c * 6;
                og[0] = mass / (area + 1e-8f); og[1] = mass; og[2] = area;
                og[3] = w0v; og[4] = qx; og[5] = qy;
            }
        }
    }
}

// ---------------------------------------------------------------------------
// cl_f = t1*sigma + sc*(mu+b2) + bfc + u@W2 + t1@Wvf   (Wvf = Wv@Wfc)
// grid=2048, block=256. Stage-1 streams straight from global.
// ---------------------------------------------------------------------------
__global__ __launch_bounds__(256, 4) void final_v3(const float* __restrict__ inF,
                                                   const float* __restrict__ H1,
                                                   const float* __restrict__ CLMM,
                                                   const float* __restrict__ stats1,
                                                   const float* __restrict__ W2,
                                                   const float* __restrict__ b2,
                                                   const float* __restrict__ Wvf,
                                                   const float* __restrict__ bfc,
                                                   float* __restrict__ oCLF)
{
    __shared__ float sU[8 * 129];
    __shared__ float sT[8 * 129];
    __shared__ float sP[8 * 129];
    int t = threadIdx.x, w = blockIdx.x;
    int bidx = w >> 8;
    int wv = t >> 6, lane = t & 63;
    int ch = lane + 64 * (wv & 1);

    float mmL[8];
#pragma unroll
    for (int c = 0; c < 8; c++)
        mmL[c] = CLMM[(long)w * 512 + c * 64 + lane];

    float mu = stats1[(bidx * 4 + (ch >> 5)) * 2];
    float rs = stats1[(bidx * 4 + (ch >> 5)) * 2 + 1];

    // ---- stage 1: K=64 GEMVs straight from global ----
    float acc1[8];
#pragma unroll
    for (int c = 0; c < 8; c++) acc1[c] = 0.f;
    if (wv < 2) {
        const float* src = H1 + (long)w * 8192 + ch;
#pragma unroll 4
        for (int j = 0; j < 64; j++) {
            float f = src[j * 128];
#pragma unroll
            for (int c = 0; c < 8; c++)
                acc1[c] = fmaf(rlane(mmL[c], j), f, acc1[c]);
        }
#pragma unroll
        for (int c = 0; c < 8; c++) sU[c * 129 + ch] = acc1[c];
    } else {
        const float* src = inF + (long)w * 8192 + ch;
#pragma unroll 4
        for (int j = 0; j < 64; j++) {
            float f = (src[j * 128] - mu) * rs;
#pragma unroll
            for (int c = 0; c < 8; c++)
                acc1[c] = fmaf(rlane(mmL[c], j), f, acc1[c]);
        }
#pragma unroll
        for (int c = 0; c < 8; c++) sT[c * 129 + ch] = acc1[c];
    }
    __syncthreads();
    // ---- stage 2: K=128 GEMVs with global weights ----
    float xL0[8], xL1[8];
    {
        const float* s2 = (wv < 2) ? sU : sT;
#pragma unroll
        for (int c = 0; c < 8; c++) {
            xL0[c] = s2[c * 129 + lane];
            xL1[c] = s2[c * 129 + 64 + lane];
        }
    }
    const float* Wm = (wv < 2) ? W2 : Wvf;
    float acc2[8];
#pragma unroll
    for (int c = 0; c < 8; c++) acc2[c] = 0.f;
#pragma unroll 2
    for (int k = 0; k < 64; k++) {
        float wk = Wm[k * 128 + ch];
#pragma unroll
        for (int c = 0; c < 8; c++)
            acc2[c] = fmaf(rlane(xL0[c], k), wk, acc2[c]);
    }
#pragma unroll 2
    for (int k = 0; k < 64; k++) {
        float wk = Wm[(k + 64) * 128 + ch];
#pragma unroll
        for (int c = 0; c < 8; c++)
            acc2[c] = fmaf(rlane(xL1[c], k), wk, acc2[c]);
    }
    if (wv >= 2) {
        // + t1 * sigma  (t1[c][ch] is this lane's own value)
        float sig = 1.0f / rs;
#pragma unroll
        for (int c = 0; c < 8; c++) {
            float t1ch = (wv & 1) ? xL1[c] : xL0[c];
            acc2[c] = fmaf(t1ch, sig, acc2[c]);
        }
#pragma unroll
        for (int c = 0; c < 8; c++) sP[c * 129 + ch] = acc2[c];
    }
    __syncthreads();
    if (wv < 2) {
        float scv[8];
#pragma unroll
        for (int c = 0; c < 8; c++) {
            float s = mmL[c];
            for (int off = 1; off < 64; off <<= 1) s += __shfl_xor(s, off);
            scv[c] = s;
        }
        float mub = mu + b2[ch];
        float bfv = bfc[ch];
#pragma unroll
        for (int c = 0; c < 8; c++) {
            float o = acc2[c] + sP[c * 129 + ch] + scv[c] * mub + bfv;
            oCLF[(long)w * 1024 + c * 128 + ch] = o;
        }
    }
}

// ---------------------------------------------------------------------------
extern "C" void kernel_launch(void* const* d_in, const int* in_sizes, int n_in,
                              void* d_out, int out_size, void* d_ws, size_t ws_size,
                              hipStream_t stream)
{
    (void)in_sizes; (void)n_in; (void)out_size; (void)ws_size;
    const float* in_f   = (const float*)d_in[0];
    const float* in_geo = (const float*)d_in[1];
    const float* W1  = (const float*)d_in[2];
    const float* b1  = (const float*)d_in[3];
    const float* W2  = (const float*)d_in[4];
    const float* b2  = (const float*)d_in[5];
    const float* Wfc = (const float*)d_in[6];
    const float* bfc = (const float*)d_in[7];
    const float* Wq  = (const float*)d_in[8];
    const float* Wv  = (const float*)d_in[9];
    float* out = (float*)d_out;
    float* ws  = (float*)d_ws;

    // workspace (floats)
    float* qh     = ws;                    // 16,777,216 (h1)
    float* clmm   = ws + 16777216;         //  1,048,576 (WThi/WTlo early, then clmm)
    float* stats1 = ws + 17825792;         //  64
    float* stats2 = ws + 17825856;         //  64
    float* wvf    = ws + 17825920;         //  16,384
    float* part   = ws + 17842304;         //  8,192

    // WT hi/lo bf16 planes (256 cols x 128 k, ushort) stashed in clmm region:
    // consumed by gemm_mfma_dual (dispatch 4) before cluster_v3 (dispatch 7)
    // overwrites clmm.
    unsigned short* wthi = (unsigned short*)clmm;            // 65,536 B
    unsigned short* wtlo = ((unsigned short*)clmm) + 32768;  // 65,536 B

    // output layout (floats)
    float* o_clf  = out;                   // (8,256,8,128)
    float* o_clm  = out + 2097152;         // (8,256,8,64)
    float* o_geo  = out + 3145728;         // (8,256,8,6)
    float* o_clr  = out + 3244032;         // (8,256,7,1)
    float* o_comp = out + 3258368;         // (8,256,8,1)
    float* o_af   = out + 3274752;         // (8,256,64,64)
    float* o_scm  = out + 11663360;        // (8,256,1,64)
    float* o_q    = out + 11794432;        // (8,256,64,128)

    gn_partial_k<<<dim3(64, 32), 256, 0, stream>>>(in_f, part);
    gn_final_k<<<32, 64, 0, stream>>>(part, stats1, 64);
    wvf_prep_k<<<32, 256, 0, stream>>>(Wv, Wfc, wvf);
    wsplit_prep_k<<<128, 256, 0, stream>>>(W1, Wq, wthi, wtlo);
    // h1 = leaky(gn1(in_f)@W1 + b1) -> qh;  qraw = gn1(in_f)@Wq -> o_q (+stats2 partials)
    gemm_mfma_dual<<<1024, 512, 0, stream>>>(in_f, wthi, wtlo, b1, stats1, qh, o_q, part);
    gn_final_k<<<32, 64, 0, stream>>>(part, stats2, 128);
    // attn normalizes qraw IN PLACE in o_q and emits af
    attn_v2<<<1024, 256, 0, stream>>>(o_q, stats2, o_q, o_af);
    cluster_v3<<<2048, 256, 0, stream>>>(o_af, in_geo, o_clm, o_clr, o_comp, o_geo,
                                         o_scm, clmm);
    final_v3<<<2048, 256, 0, stream>>>(in_f, qh, clmm, stats1, W2, b2, wvf, bfc, o_clf);
}

// Round 6
// 369.969 us; speedup vs baseline: 1.3109x; 1.0659x over previous
//
#include <hip/hip_runtime.h>

#define TWO_PI_F 6.28318530717958647692f
#define SCL_F    0.02209708691207961f   // TEMP/SCALE/sqrt(128)

typedef __attribute__((ext_vector_type(8))) short s16x8;
typedef __attribute__((ext_vector_type(4))) float f32x4;

__device__ __forceinline__ float rlane(float v, int l) {
    return __uint_as_float((unsigned)__builtin_amdgcn_readlane((int)__float_as_uint(v), l));
}

__device__ __forceinline__ unsigned short f2bf(float f) {
    unsigned u = __float_as_uint(f);
    return (unsigned short)((u + 0x7fff + ((u >> 16) & 1)) >> 16);
}
__device__ __forceinline__ float bf2f(unsigned short h) {
    return __uint_as_float(((unsigned)h) << 16);
}

// ---------------------------------------------------------------------------
// Group-norm partial stats for in_f: per (b,g) over 16384 rows x 32 ch.
// grid=(64,32), block=256
// ---------------------------------------------------------------------------
__global__ __launch_bounds__(256) void gn_partial_k(const float* __restrict__ X,
                                                    float* __restrict__ partials)
{
    int t = threadIdx.x;
    int chunk = blockIdx.x;
    int grp = blockIdx.y;          // b*4+g
    int b = grp >> 2, g = grp & 3;
    const float* base = X + ((long)b * 16384 + (long)chunk * 256) * 128 + g * 32;
    float s = 0.f, ss = 0.f;
#pragma unroll
    for (int i = 0; i < 8; i++) {
        int rl_ = i * 32 + (t >> 3);
        int c4 = (t & 7) * 4;
        float4 v = *(const float4*)(base + (long)rl_ * 128 + c4);
        s  += v.x + v.y + v.z + v.w;
        ss += v.x * v.x + v.y * v.y + v.z * v.z + v.w * v.w;
    }
    __shared__ float r0[256], r1[256];
    r0[t] = s; r1[t] = ss;
    __syncthreads();
    for (int off = 128; off > 0; off >>= 1) {
        if (t < off) { r0[t] += r0[t + off]; r1[t] += r1[t + off]; }
        __syncthreads();
    }
    if (t == 0) {
        partials[(grp * 64 + chunk) * 2]     = r0[0];
        partials[(grp * 64 + chunk) * 2 + 1] = r1[0];
    }
}

// grid=32, block=64; nblk partials per group
__global__ void gn_final_k(const float* __restrict__ partials, float* __restrict__ stats,
                           int nblk)
{
    int grp = blockIdx.x, t = threadIdx.x;
    float s = 0.f, ss = 0.f;
    for (int i = t; i < nblk; i += 64) {
        s  += partials[(grp * nblk + i) * 2];
        ss += partials[(grp * nblk + i) * 2 + 1];
    }
    for (int off = 1; off < 64; off <<= 1) { s += __shfl_xor(s, off); ss += __shfl_xor(ss, off); }
    if (t == 0) {
        const float N = 524288.0f;
        float mu = s / N;
        float var = ss / N - mu * mu;
        stats[grp * 2]     = mu;
        stats[grp * 2 + 1] = 1.0f / sqrtf(var + 0.001f);
    }
}

// ---------------------------------------------------------------------------
// Wvf = Wv @ Wfc  (128x128). grid=32 blocks x 256 threads (4 rows/block).
// ---------------------------------------------------------------------------
__global__ __launch_bounds__(256) void wvf_prep_k(const float* __restrict__ Wv,
                                                  const float* __restrict__ Wfc,
                                                  float* __restrict__ out)
{
    int t = threadIdx.x;
    int rr = t >> 6, cl = t & 63;
    int r = blockIdx.x * 4 + rr;
    float a0 = 0.f, a1 = 0.f;
    for (int k = 0; k < 128; k++) {
        float wv = Wv[r * 128 + k];
        a0 = fmaf(wv, Wfc[k * 128 + cl], a0);
        a1 = fmaf(wv, Wfc[k * 128 + 64 + cl], a1);
    }
    out[r * 128 + cl] = a0;
    out[r * 128 + 64 + cl] = a1;
}

// ---------------------------------------------------------------------------
// Split Bcat = [W1 | Wq] (stored [k][n] row-major) into bf16 hi/lo planes,
// TRANSPOSED: WT*[col][k], col 0..255 (0-127 = W1 cols, 128-255 = Wq cols).
// grid=128, block=256.
// ---------------------------------------------------------------------------
__global__ __launch_bounds__(256) void wsplit_prep_k(const float* __restrict__ W1,
                                                     const float* __restrict__ Wq,
                                                     unsigned short* __restrict__ WThi,
                                                     unsigned short* __restrict__ WTlo)
{
    int idx = blockIdx.x * 256 + threadIdx.x;   // 32768 total
    int col = idx >> 7, k = idx & 127;
    float w = (col < 128) ? W1[k * 128 + col] : Wq[k * 128 + (col - 128)];
    unsigned short hb = f2bf(w);
    float hf = bf2f(hb);
    WThi[col * 128 + k] = hb;
    WTlo[col * 128 + k] = f2bf(w - hf);
}

// ---------------------------------------------------------------------------
// MFMA dual GEMM via bf16 hi/lo split: C = gn1(X) @ [W1|Wq] with
//   C ~= Ahi@Bhi + Alo@Bhi + Ahi@Blo   (error ~1e-5 rel, near-fp32).
// grid=1024 (128 rows/block), block=512 (8 waves).
// ---------------------------------------------------------------------------
__global__ __launch_bounds__(512, 4) void gemm_mfma_dual(const float* __restrict__ X,
                                                         const unsigned short* __restrict__ WThi,
                                                         const unsigned short* __restrict__ WTlo,
                                                         const float* __restrict__ b1,
                                                         const float* __restrict__ stats,
                                                         float* __restrict__ C1,
                                                         float* __restrict__ C2,
                                                         float* __restrict__ statsout)
{
    __shared__ short sAhi[128 * 40];   // [row][k] bf16, stride 40 (pad)
    __shared__ short sAlo[128 * 40];
    __shared__ short sBhi[256 * 40];   // [col][k] bf16, stride 40
    __shared__ short sBlo[256 * 40];
    int t = threadIdx.x;
    int wv = t >> 6, lane = t & 63;
    int half = wv >> 2;                // 0 -> W1, 1 -> Wq
    int mrow0 = (wv & 3) * 32;
    long row0 = (long)blockIdx.x * 128;
    int bidx = (int)(row0 >> 14);

    float muv[4], rsv[4];
#pragma unroll
    for (int g = 0; g < 4; g++) {
        muv[g] = stats[(bidx * 4 + g) * 2];
        rsv[g] = stats[(bidx * 4 + g) * 2 + 1];
    }

    f32x4 acc[2][8];
#pragma unroll
    for (int m2 = 0; m2 < 2; m2++)
#pragma unroll
        for (int nt = 0; nt < 8; nt++) acc[m2][nt] = (f32x4){0.f, 0.f, 0.f, 0.f};

    int lr = lane & 15, lk = (lane >> 4) * 8;
    // staging assignments
    int arow = t >> 2, akq = (t & 3) * 8;        // A: 128 rows x 32 k, 8 elems/thr
    int bcol = t >> 1, bko = (t & 1) * 16;       // B: 256 cols x 32 k, 16 elems/thr/plane
    const float* xsrc = X + (row0 + arow) * 128;

    for (int kt = 0; kt < 4; kt++) {
        // ---- stage A (normalize, split hi/lo) ----
        {
            float mu = muv[kt], rs = rsv[kt];
            float4 x0 = *(const float4*)(xsrc + kt * 32 + akq);
            float4 x1 = *(const float4*)(xsrc + kt * 32 + akq + 4);
            float v[8];
            v[0] = x0.x; v[1] = x0.y; v[2] = x0.z; v[3] = x0.w;
            v[4] = x1.x; v[5] = x1.y; v[6] = x1.z; v[7] = x1.w;
            s16x8 vh, vl;
#pragma unroll
            for (int j = 0; j < 8; j++) {
                float x = (v[j] - mu) * rs;
                unsigned short hb = f2bf(x);
                float hf = bf2f(hb);
                unsigned short lb = f2bf(x - hf);
                vh[j] = (short)hb;
                vl[j] = (short)lb;
            }
            *(s16x8*)&sAhi[arow * 40 + akq] = vh;
            *(s16x8*)&sAlo[arow * 40 + akq] = vl;
        }
        // ---- stage B (copy pre-split planes) ----
        {
            const unsigned short* sh = WThi + bcol * 128 + kt * 32 + bko;
            const unsigned short* sl = WTlo + bcol * 128 + kt * 32 + bko;
            *(s16x8*)&sBhi[bcol * 40 + bko]     = *(const s16x8*)(sh);
            *(s16x8*)&sBhi[bcol * 40 + bko + 8] = *(const s16x8*)(sh + 8);
            *(s16x8*)&sBlo[bcol * 40 + bko]     = *(const s16x8*)(sl);
            *(s16x8*)&sBlo[bcol * 40 + bko + 8] = *(const s16x8*)(sl + 8);
        }
        __syncthreads();
        // ---- fragments + MFMA ----
        s16x8 ahi[2], alo[2];
#pragma unroll
        for (int m2 = 0; m2 < 2; m2++) {
            int row = mrow0 + m2 * 16 + lr;
            ahi[m2] = *(const s16x8*)&sAhi[row * 40 + lk];
            alo[m2] = *(const s16x8*)&sAlo[row * 40 + lk];
        }
#pragma unroll
        for (int nt = 0; nt < 8; nt++) {
            int col = half * 128 + nt * 16 + lr;
            s16x8 bhi = *(const s16x8*)&sBhi[col * 40 + lk];
            s16x8 blo = *(const s16x8*)&sBlo[col * 40 + lk];
#pragma unroll
            for (int m2 = 0; m2 < 2; m2++) {
                acc[m2][nt] = __builtin_amdgcn_mfma_f32_16x16x32_bf16(ahi[m2], bhi, acc[m2][nt], 0, 0, 0);
                acc[m2][nt] = __builtin_amdgcn_mfma_f32_16x16x32_bf16(alo[m2], bhi, acc[m2][nt], 0, 0, 0);
                acc[m2][nt] = __builtin_amdgcn_mfma_f32_16x16x32_bf16(ahi[m2], blo, acc[m2][nt], 0, 0, 0);
            }
        }
        __syncthreads();
    }

    // ---- epilogue: bias/leaky + store ----
    int rg4 = (lane >> 4) * 4;
    float* C = half ? C2 : C1;
    float bv[8];
    if (half == 0) {
#pragma unroll
        for (int nt = 0; nt < 8; nt++) bv[nt] = b1[nt * 16 + lr];
    }
#pragma unroll
    for (int m2 = 0; m2 < 2; m2++) {
        long rbase = row0 + mrow0 + m2 * 16 + rg4;
#pragma unroll
        for (int nt = 0; nt < 8; nt++) {
#pragma unroll
            for (int r = 0; r < 4; r++) {
                float v = acc[m2][nt][r];
                if (half == 0) {
                    v += bv[nt];
                    v = (v >= 0.f) ? v : 0.01f * v;
                }
                C[(rbase + r) * 128 + nt * 16 + lr] = v;
            }
        }
    }
    // ---- fused gn2 partial stats from the Wq half ----
    float s4[4] = {0.f, 0.f, 0.f, 0.f}, ss4[4] = {0.f, 0.f, 0.f, 0.f};
    if (half == 1) {
#pragma unroll
        for (int m2 = 0; m2 < 2; m2++)
#pragma unroll
            for (int nt = 0; nt < 8; nt++) {
                int g = nt >> 1;
#pragma unroll
                for (int r = 0; r < 4; r++) {
                    float v = acc[m2][nt][r];
                    s4[g] += v; ss4[g] += v * v;
                }
            }
    }
    __syncthreads();
    float* sRed = (float*)sAhi;   // 8 KB needed <= 10,240 B; sA dead
    if (half == 1) {
        int q = t & 255;
#pragma unroll
        for (int g = 0; g < 4; g++) {
            sRed[q * 8 + 2 * g]     = s4[g];
            sRed[q * 8 + 2 * g + 1] = ss4[g];
        }
    }
    __syncthreads();
    if (t < 8) {
        int g = t >> 1, which = t & 1;
        float a2 = 0.f;
        for (int u = 0; u < 256; u++) a2 += sRed[u * 8 + 2 * g + which];
        statsout[((bidx * 4 + g) * 128 + (int)(blockIdx.x & 127)) * 2 + which] = a2;
    }
}

// ---------------------------------------------------------------------------
// attn_v3: q = gn2(qraw) -> outQ (in place); S = sq_dist(q,q) via bf16 hi/lo
// MFMA Gram matrix (mu cancels in distances; rs is already folded into q);
// softmax + min-max -> af.
// grid=2048 (1 window/block), block=256 (4 waves).
// Waves: stage q (fp32 out + bf16 hi/lo LDS + per-row norms via quad shfl),
// wave wv computes S-tile rows wv*16..+15 (4x 16x16 tiles, K=128, 3 mfma per
// k-chunk for hi*hi + lo*hi + hi*lo). S written to sS (aliased over the dead
// lo-plane, stride 68 = conflict-free), epilogue 4 threads/row, single LDS
// read pass, exp/sum/minmax in registers.
// LDS = 41,216 B -> 3 blocks/CU (12 waves/CU vs attn_v2's 8).
// ---------------------------------------------------------------------------
__global__ __launch_bounds__(256, 3) void attn_v3(const float* __restrict__ Qraw,
                                                  const float* __restrict__ stats,
                                                  float* __restrict__ outQ,
                                                  float* __restrict__ outAF)
{
    __shared__ short sYhi[4 * 64 * 40];   // [kchunk][row][40]
    __shared__ short sYlo[4 * 64 * 40];
    __shared__ float sN[64];
    float* sS = (float*)sYlo;             // alias after MFMA: [row][68]
    int t = threadIdx.x;
    int wv = t >> 6, lane = t & 63;
    int w = blockIdx.x;
    int bidx = w >> 8;

    // ---- stage: row = t>>2, kchunk = t&3 (kchunk == gn group) ----
    {
        int row = t >> 2, kc = t & 3;
        float mu = stats[(bidx * 4 + kc) * 2];
        float rs = stats[(bidx * 4 + kc) * 2 + 1];
        const float* src = Qraw + (long)w * 8192 + row * 128 + kc * 32;
        float* dstG = outQ + (long)w * 8192 + row * 128 + kc * 32;
        s16x8 vh[4], vl[4];
        float n = 0.f;
#pragma unroll
        for (int q4 = 0; q4 < 8; q4++) {
            float4 v = *(const float4*)(src + 4 * q4);
            float vv[4] = {v.x, v.y, v.z, v.w};
            float4 o;
#pragma unroll
            for (int e = 0; e < 4; e++) {
                float x = (vv[e] - mu) * rs;
                (&o.x)[e] = x;
                n += x * x;
                unsigned short hb = f2bf(x);
                float hf = bf2f(hb);
                int kk = q4 * 4 + e;
                vh[kk >> 3][kk & 7] = (short)hb;
                vl[kk >> 3][kk & 7] = (short)f2bf(x - hf);
            }
            *(float4*)(dstG + 4 * q4) = o;
        }
        int base = (kc * 64 + row) * 40;
#pragma unroll
        for (int u = 0; u < 4; u++) {
            *(s16x8*)&sYhi[base + u * 8] = vh[u];
            *(s16x8*)&sYlo[base + u * 8] = vl[u];
        }
        // quad-reduce the row norm (lanes 4r..4r+3 share a row)
        n += __shfl_xor(n, 1);
        n += __shfl_xor(n, 2);
        if (kc == 0) sN[row] = n;
    }
    __syncthreads();

    // ---- Gram via MFMA: wave wv owns rows wv*16..+15, 4 col-tiles ----
    f32x4 acc[4];
#pragma unroll
    for (int nt = 0; nt < 4; nt++) acc[nt] = (f32x4){0.f, 0.f, 0.f, 0.f};
    int lr = lane & 15, lk = (lane >> 4) * 8;
    for (int kc = 0; kc < 4; kc++) {
        int abase = (kc * 64 + wv * 16 + lr) * 40 + lk;
        s16x8 ahi = *(const s16x8*)&sYhi[abase];
        s16x8 alo = *(const s16x8*)&sYlo[abase];
#pragma unroll
        for (int nt = 0; nt < 4; nt++) {
            int bbase = (kc * 64 + nt * 16 + lr) * 40 + lk;
            s16x8 bhi = *(const s16x8*)&sYhi[bbase];
            s16x8 blo = *(const s16x8*)&sYlo[bbase];
            acc[nt] = __builtin_amdgcn_mfma_f32_16x16x32_bf16(ahi, bhi, acc[nt], 0, 0, 0);
            acc[nt] = __builtin_amdgcn_mfma_f32_16x16x32_bf16(alo, bhi, acc[nt], 0, 0, 0);
            acc[nt] = __builtin_amdgcn_mfma_f32_16x16x32_bf16(ahi, blo, acc[nt], 0, 0, 0);
        }
    }
    __syncthreads();   // all waves done reading sYlo before aliasing

    // ---- S = n_r + n_c - 2*dot -> sS[row][68] ----
    {
        float nrow[4];
        int r0 = wv * 16 + (lane >> 4) * 4;
#pragma unroll
        for (int r = 0; r < 4; r++) nrow[r] = sN[r0 + r];
#pragma unroll
        for (int nt = 0; nt < 4; nt++) {
            float ncol = sN[nt * 16 + lr];
#pragma unroll
            for (int r = 0; r < 4; r++)
                sS[(r0 + r) * 68 + nt * 16 + lr] = nrow[r] + ncol - 2.f * acc[nt][r];
        }
    }
    __syncthreads();

    // ---- epilogue: 4 threads/row, single read pass, regs thereafter ----
    {
        int row = t >> 2, j0 = (t & 3) * 16;
        float p[16];
#pragma unroll
        for (int q = 0; q < 4; q++) {
            float4 v = *(const float4*)&sS[row * 68 + j0 + 4 * q];
            p[4 * q + 0] = v.x; p[4 * q + 1] = v.y;
            p[4 * q + 2] = v.z; p[4 * q + 3] = v.w;
        }
        float mn = p[0];
#pragma unroll
        for (int i = 1; i < 16; i++) mn = fminf(mn, p[i]);
        mn = fminf(mn, __shfl_xor(mn, 1));
        mn = fminf(mn, __shfl_xor(mn, 2));
        float sum = 0.f, pmx = -1.f, pmn = 1e30f;
#pragma unroll
        for (int i = 0; i < 16; i++) {
            float e = expf(-SCL_F * (p[i] - mn));
            p[i] = e;
            sum += e;
            pmx = fmaxf(pmx, e);
            pmn = fminf(pmn, e);
        }
        sum += __shfl_xor(sum, 1); sum += __shfl_xor(sum, 2);
        pmx = fmaxf(pmx, __shfl_xor(pmx, 1)); pmx = fmaxf(pmx, __shfl_xor(pmx, 2));
        pmn = fminf(pmn, __shfl_xor(pmn, 1)); pmn = fminf(pmn, __shfl_xor(pmn, 2));
        float rsum = 1.0f / sum;
        float amn = pmn * rsum, amx = pmx * rsum;
        float dinv = 1.0f / (amx - amn + 1e-8f);
        float* dst = outAF + (long)w * 4096 + row * 64 + j0;
#pragma unroll
        for (int q = 0; q < 4; q++) {
            float4 o;
            o.x = (p[4 * q + 0] * rsum - amn) * dinv;
            o.y = (p[4 * q + 1] * rsum - amn) * dinv;
            o.z = (p[4 * q + 2] * rsum - amn) * dinv;
            o.w = (p[4 * q + 3] * rsum - amn) * dinv;
            *(float4*)(dst + 4 * q) = o;
        }
    }
}

// ---------------------------------------------------------------------------
// Per-window clustering, register/readlane rewrite (DS-minimized).
// grid=2048, block=256.
// ---------------------------------------------------------------------------
__global__ __launch_bounds__(256, 4) void cluster_v3(const float* __restrict__ AF,
                                                     const float* __restrict__ GEO,
                                                     float* __restrict__ oCLM,
                                                     float* __restrict__ oCLR,
                                                     float* __restrict__ oCOMP,
                                                     float* __restrict__ oGEO,
                                                     float* __restrict__ oSCM,
                                                     float* __restrict__ wCLMM)
{
    __shared__ float sAF[64 * 65];
    __shared__ float sPart[4 * 64 * 3];
    __shared__ float sCLM[8 * 65];
    int t = threadIdx.x, w = blockIdx.x;
    int wv = t >> 6, lane = t & 63;
    const float* afw = AF + (long)w * 4096;
#pragma unroll
    for (int i = 0; i < 4; i++) {
        int f4 = i * 256 + t;
        float4 v = *(const float4*)(afw + f4 * 4);
        int r = f4 >> 4, c4 = (f4 & 15) * 4;
        float* dst = &sAF[r * 65 + c4];
        dst[0] = fminf(fmaxf(v.x, 1e-5f), 0.99999f);
        dst[1] = fminf(fmaxf(v.y, 1e-5f), 0.99999f);
        dst[2] = fminf(fmaxf(v.z, 1e-5f), 0.99999f);
        dst[3] = fminf(fmaxf(v.w, 1e-5f), 0.99999f);
    }
    // per-lane geo row (lane = element index)
    const float* gp = GEO + ((long)w * 64 + lane) * 6;
    float2 g01 = *(const float2*)(gp);
    float2 g23 = *(const float2*)(gp + 2);
    float2 g45 = *(const float2*)(gp + 4);
    float gD = g01.x, gA = g23.x, gI = g23.y, gX = g45.x, gY = g45.y;
    __syncthreads();

    // ---- phase 1 ----
    const float* afrow = &sAF[lane * 65];
    float dk[16], ak[16], T[16];
    float v0 = 0.f, v1 = 0.f;
#pragma unroll
    for (int kk = 0; kk < 16; kk++) {
        int kc = kk * 4 + wv;
        float afk = afrow[kc];
        float d = afk * rlane(gD, kc);
        float a = afk * rlane(gA, kc);
        dk[kk] = d; ak[kk] = a; T[kk] = 0.f;
        float m = d * a;
        float dx = gX - rlane(gX, kc), dy = gY - rlane(gY, kc);
        v0 += d * rlane(gI, kc) + m * (dx * dx + dy * dy);
        v1 += m * a;
    }
    for (int jq = 0; jq < 16; jq++) {
        float dj[4], aj[4];
#pragma unroll
        for (int jr = 0; jr < 4; jr++) {
            int j = jq * 4 + jr;
            float afj = afrow[j];
            dj[jr] = afj * rlane(gD, j);
            aj[jr] = afj * rlane(gA, j);
        }
#pragma unroll
        for (int kk = 0; kk < 16; kk++) {
            if (kk > jq) {
#pragma unroll
                for (int jr = 0; jr < 4; jr++)
                    T[kk] = fmaf(aj[jr], fminf(dj[jr], dk[kk]), T[kk]);
            } else if (kk == jq) {
                if (0 < wv) T[kk] = fmaf(aj[0], fminf(dj[0], dk[kk]), T[kk]);
                if (1 < wv) T[kk] = fmaf(aj[1], fminf(dj[1], dk[kk]), T[kk]);
                if (2 < wv) T[kk] = fmaf(aj[2], fminf(dj[2], dk[kk]), T[kk]);
            }
        }
    }
    float S = 0.f;
#pragma unroll
    for (int kk = 0; kk < 16; kk++) S = fmaf(ak[kk], T[kk], S);
    {
        float* p = &sPart[(wv * 64 + lane) * 3];
        p[0] = v0; p[1] = v1; p[2] = S;
    }
    __syncthreads();

    // ---- combine + greedy selection (wave 0) ----
    if (t < 64) {
        int k = lane;
        float c0 = 0.f, c1 = 0.f, c2 = 0.f;
#pragma unroll
        for (int u = 0; u < 4; u++) {
            const float* p = &sPart[(u * 64 + k) * 3];
            c0 += p[0]; c1 += p[1]; c2 += p[2];
        }
        float compk = ((c1 + 2.f * c2) / TWO_PI_F) / c0;
        float sc = 1.0f;
        for (int c = 0; c < 7; c++) {
            float score = compk * sc;
            float mx = score;
            for (int off = 1; off < 64; off <<= 1) mx = fmaxf(mx, __shfl_xor(mx, off));
            unsigned long long bl = __ballot(score == mx);
            int idx = __ffsll(bl) - 1;
            float rowk = sAF[idx * 65 + k];
            float clm = sc * rowk;
            sCLM[c * 65 + k] = clm;
            oCLM[(long)w * 512 + c * 64 + k] = clm;
            if (k == 0) oCLR[(long)w * 7 + c] = (float)idx;
            sc *= (1.0f - rowk);
        }
        sCLM[7 * 65 + k] = sc;
        oCLM[(long)w * 512 + 448 + k] = sc;
        oSCM[(long)w * 64 + k] = sc;
    }
    __syncthreads();

    // ---- phase 3: cluster aggregates + second compactness (2 clusters/wave) ----
    {
        int k = lane;
        for (int cc = 0; cc < 2; cc++) {
            int c = wv + cc * 4;
            float clm = sCLM[c * 65 + k];
            float cd = clm * gD, ca = clm * gA;
            float cm = cd * ca;
            float T3 = 0.f;
            for (int j = 0; j < 64; j++)
                T3 = fmaf(rlane(ca, j), fminf(rlane(cd, j), cd), T3);
            float r0 = cm, r1 = ca, r2c = cm * gX, r3 = cm * gY, r4 = clm;
            float r5 = cm * ca;
            float r6 = ca * T3 - ca * ca * cd;   // 2*S contribution (self removed)
            for (int off = 1; off < 64; off <<= 1) {
                r0 += __shfl_xor(r0, off); r1 += __shfl_xor(r1, off);
                r2c += __shfl_xor(r2c, off); r3 += __shfl_xor(r3, off);
                r4 += __shfl_xor(r4, off); r5 += __shfl_xor(r5, off);
                r6 += __shfl_xor(r6, off);
            }
            float mass = r0, area = r1;
            float qx = r2c / (mass + 1e-8f), qy = r3 / (mass + 1e-8f);
            wCLMM[(long)w * 512 + c * 64 + k] = clm / (r4 + 1e-8f);
            float dx = qx - gX, dy = qy - gY;
            float w0v = cd * gI + cm * (dx * dx + dy * dy);
            for (int off = 1; off < 64; off <<= 1) w0v += __shfl_xor(w0v, off);
            if (k == 0) {
                oCOMP[(long)w * 8 + c] = ((r5 + r6) / TWO_PI_F) / w0v;
                float* og = oGEO + (long)w * 48 + c * 6;
                og[0] = mass / (area + 1e-8f); og[1] = mass; og[2] = area;
                og[3] = w0v; og[4] = qx; og[5] = qy;
            }
        }
    }
}

// ---------------------------------------------------------------------------
// cl_f = t1*sigma + sc*(mu+b2) + bfc + u@W2 + t1@Wvf   (Wvf = Wv@Wfc)
// grid=2048, block=256. Stage-1 streams straight from global.
// ---------------------------------------------------------------------------
__global__ __launch_bounds__(256, 4) void final_v3(const float* __restrict__ inF,
                                                   const float* __restrict__ H1,
                                                   const float* __restrict__ CLMM,
                                                   const float* __restrict__ stats1,
                                                   const float* __restrict__ W2,
                                                   const float* __restrict__ b2,
                                                   const float* __restrict__ Wvf,
                                                   const float* __restrict__ bfc,
                                                   float* __restrict__ oCLF)
{
    __shared__ float sU[8 * 129];
    __shared__ float sT[8 * 129];
    __shared__ float sP[8 * 129];
    int t = threadIdx.x, w = blockIdx.x;
    int bidx = w >> 8;
    int wv = t >> 6, lane = t & 63;
    int ch = lane + 64 * (wv & 1);

    float mmL[8];
#pragma unroll
    for (int c = 0; c < 8; c++)
        mmL[c] = CLMM[(long)w * 512 + c * 64 + lane];

    float mu = stats1[(bidx * 4 + (ch >> 5)) * 2];
    float rs = stats1[(bidx * 4 + (ch >> 5)) * 2 + 1];

    // ---- stage 1: K=64 GEMVs straight from global ----
    float acc1[8];
#pragma unroll
    for (int c = 0; c < 8; c++) acc1[c] = 0.f;
    if (wv < 2) {
        const float* src = H1 + (long)w * 8192 + ch;
#pragma unroll 4
        for (int j = 0; j < 64; j++) {
            float f = src[j * 128];
#pragma unroll
            for (int c = 0; c < 8; c++)
                acc1[c] = fmaf(rlane(mmL[c], j), f, acc1[c]);
        }
#pragma unroll
        for (int c = 0; c < 8; c++) sU[c * 129 + ch] = acc1[c];
    } else {
        const float* src = inF + (long)w * 8192 + ch;
#pragma unroll 4
        for (int j = 0; j < 64; j++) {
            float f = (src[j * 128] - mu) * rs;
#pragma unroll
            for (int c = 0; c < 8; c++)
                acc1[c] = fmaf(rlane(mmL[c], j), f, acc1[c]);
        }
#pragma unroll
        for (int c = 0; c < 8; c++) sT[c * 129 + ch] = acc1[c];
    }
    __syncthreads();
    // ---- stage 2: K=128 GEMVs with global weights ----
    float xL0[8], xL1[8];
    {
        const float* s2 = (wv < 2) ? sU : sT;
#pragma unroll
        for (int c = 0; c < 8; c++) {
            xL0[c] = s2[c * 129 + lane];
            xL1[c] = s2[c * 129 + 64 + lane];
        }
    }
    const float* Wm = (wv < 2) ? W2 : Wvf;
    float acc2[8];
#pragma unroll
    for (int c = 0; c < 8; c++) acc2[c] = 0.f;
#pragma unroll 2
    for (int k = 0; k < 64; k++) {
        float wk = Wm[k * 128 + ch];
#pragma unroll
        for (int c = 0; c < 8; c++)
            acc2[c] = fmaf(rlane(xL0[c], k), wk, acc2[c]);
    }
#pragma unroll 2
    for (int k = 0; k < 64; k++) {
        float wk = Wm[(k + 64) * 128 + ch];
#pragma unroll
        for (int c = 0; c < 8; c++)
            acc2[c] = fmaf(rlane(xL1[c], k), wk, acc2[c]);
    }
    if (wv >= 2) {
        // + t1 * sigma  (t1[c][ch] is this lane's own value)
        float sig = 1.0f / rs;
#pragma unroll
        for (int c = 0; c < 8; c++) {
            float t1ch = (wv & 1) ? xL1[c] : xL0[c];
            acc2[c] = fmaf(t1ch, sig, acc2[c]);
        }
#pragma unroll
        for (int c = 0; c < 8; c++) sP[c * 129 + ch] = acc2[c];
    }
    __syncthreads();
    if (wv < 2) {
        float scv[8];
#pragma unroll
        for (int c = 0; c < 8; c++) {
            float s = mmL[c];
            for (int off = 1; off < 64; off <<= 1) s += __shfl_xor(s, off);
            scv[c] = s;
        }
        float mub = mu + b2[ch];
        float bfv = bfc[ch];
#pragma unroll
        for (int c = 0; c < 8; c++) {
            float o = acc2[c] + sP[c * 129 + ch] + scv[c] * mub + bfv;
            oCLF[(long)w * 1024 + c * 128 + ch] = o;
        }
    }
}

// ---------------------------------------------------------------------------
extern "C" void kernel_launch(void* const* d_in, const int* in_sizes, int n_in,
                              void* d_out, int out_size, void* d_ws, size_t ws_size,
                              hipStream_t stream)
{
    (void)in_sizes; (void)n_in; (void)out_size; (void)ws_size;
    const float* in_f   = (const float*)d_in[0];
    const float* in_geo = (const float*)d_in[1];
    const float* W1  = (const float*)d_in[2];
    const float* b1  = (const float*)d_in[3];
    const float* W2  = (const float*)d_in[4];
    const float* b2  = (const float*)d_in[5];
    const float* Wfc = (const float*)d_in[6];
    const float* bfc = (const float*)d_in[7];
    const float* Wq  = (const float*)d_in[8];
    const float* Wv  = (const float*)d_in[9];
    float* out = (float*)d_out;
    float* ws  = (float*)d_ws;

    // workspace (floats)
    float* qh     = ws;                    // 16,777,216 (h1)
    float* clmm   = ws + 16777216;         //  1,048,576 (WThi/WTlo early, then clmm)
    float* stats1 = ws + 17825792;         //  64
    float* stats2 = ws + 17825856;         //  64
    float* wvf    = ws + 17825920;         //  16,384
    float* part   = ws + 17842304;         //  8,192

    // WT hi/lo bf16 planes (256 cols x 128 k, ushort) stashed in clmm region:
    // consumed by gemm_mfma_dual (dispatch 5) before cluster_v3 (dispatch 8)
    // overwrites clmm.
    unsigned short* wthi = (unsigned short*)clmm;            // 65,536 B
    unsigned short* wtlo = ((unsigned short*)clmm) + 32768;  // 65,536 B

    // output layout (floats)
    float* o_clf  = out;                   // (8,256,8,128)
    float* o_clm  = out + 2097152;         // (8,256,8,64)
    float* o_geo  = out + 3145728;         // (8,256,8,6)
    float* o_clr  = out + 3244032;         // (8,256,7,1)
    float* o_comp = out + 3258368;         // (8,256,8,1)
    float* o_af   = out + 3274752;         // (8,256,64,64)
    float* o_scm  = out + 11663360;        // (8,256,1,64)
    float* o_q    = out + 11794432;        // (8,256,64,128)

    gn_partial_k<<<dim3(64, 32), 256, 0, stream>>>(in_f, part);
    gn_final_k<<<32, 64, 0, stream>>>(part, stats1, 64);
    wvf_prep_k<<<32, 256, 0, stream>>>(Wv, Wfc, wvf);
    wsplit_prep_k<<<128, 256, 0, stream>>>(W1, Wq, wthi, wtlo);
    // h1 = leaky(gn1(in_f)@W1 + b1) -> qh;  qraw = gn1(in_f)@Wq -> o_q (+stats2 partials)
    gemm_mfma_dual<<<1024, 512, 0, stream>>>(in_f, wthi, wtlo, b1, stats1, qh, o_q, part);
    gn_final_k<<<32, 64, 0, stream>>>(part, stats2, 128);
    // attn normalizes qraw IN PLACE in o_q and emits af
    attn_v3<<<2048, 256, 0, stream>>>(o_q, stats2, o_q, o_af);
    cluster_v3<<<2048, 256, 0, stream>>>(o_af, in_geo, o_clm, o_clr, o_comp, o_geo,
                                         o_scm, clmm);
    final_v3<<<2048, 256, 0, stream>>>(in_f, qh, clmm, stats1, W2, b2, wvf, bfc, o_clf);
}

// Round 7
// 348.835 us; speedup vs baseline: 1.3903x; 1.0606x over previous
//
#include <hip/hip_runtime.h>

#define TWO_PI_F 6.28318530717958647692f
#define SCL_F    0.02209708691207961f   // TEMP/SCALE/sqrt(128)

typedef __attribute__((ext_vector_type(8))) short s16x8;
typedef __attribute__((ext_vector_type(4))) float f32x4;

__device__ __forceinline__ float rlane(float v, int l) {
    return __uint_as_float((unsigned)__builtin_amdgcn_readlane((int)__float_as_uint(v), l));
}

__device__ __forceinline__ unsigned short f2bf(float f) {
    unsigned u = __float_as_uint(f);
    return (unsigned short)((u + 0x7fff + ((u >> 16) & 1)) >> 16);
}
__device__ __forceinline__ float bf2f(unsigned short h) {
    return __uint_as_float(((unsigned)h) << 16);
}

// ---------------------------------------------------------------------------
// Group-norm partial stats for in_f: per (b,g) over 16384 rows x 32 ch.
// grid=(64,32), block=256
// ---------------------------------------------------------------------------
__global__ __launch_bounds__(256) void gn_partial_k(const float* __restrict__ X,
                                                    float* __restrict__ partials)
{
    int t = threadIdx.x;
    int chunk = blockIdx.x;
    int grp = blockIdx.y;          // b*4+g
    int b = grp >> 2, g = grp & 3;
    const float* base = X + ((long)b * 16384 + (long)chunk * 256) * 128 + g * 32;
    float s = 0.f, ss = 0.f;
#pragma unroll
    for (int i = 0; i < 8; i++) {
        int rl_ = i * 32 + (t >> 3);
        int c4 = (t & 7) * 4;
        float4 v = *(const float4*)(base + (long)rl_ * 128 + c4);
        s  += v.x + v.y + v.z + v.w;
        ss += v.x * v.x + v.y * v.y + v.z * v.z + v.w * v.w;
    }
    __shared__ float r0[256], r1[256];
    r0[t] = s; r1[t] = ss;
    __syncthreads();
    for (int off = 128; off > 0; off >>= 1) {
        if (t < off) { r0[t] += r0[t + off]; r1[t] += r1[t + off]; }
        __syncthreads();
    }
    if (t == 0) {
        partials[(grp * 64 + chunk) * 2]     = r0[0];
        partials[(grp * 64 + chunk) * 2 + 1] = r1[0];
    }
}

// grid=32, block=64; nblk partials per group
__global__ void gn_final_k(const float* __restrict__ partials, float* __restrict__ stats,
                           int nblk)
{
    int grp = blockIdx.x, t = threadIdx.x;
    float s = 0.f, ss = 0.f;
    for (int i = t; i < nblk; i += 64) {
        s  += partials[(grp * nblk + i) * 2];
        ss += partials[(grp * nblk + i) * 2 + 1];
    }
    for (int off = 1; off < 64; off <<= 1) { s += __shfl_xor(s, off); ss += __shfl_xor(ss, off); }
    if (t == 0) {
        const float N = 524288.0f;
        float mu = s / N;
        float var = ss / N - mu * mu;
        stats[grp * 2]     = mu;
        stats[grp * 2 + 1] = 1.0f / sqrtf(var + 0.001f);
    }
}

// ---------------------------------------------------------------------------
// Wvf = Wv @ Wfc  (128x128). grid=32 blocks x 256 threads (4 rows/block).
// ---------------------------------------------------------------------------
__global__ __launch_bounds__(256) void wvf_prep_k(const float* __restrict__ Wv,
                                                  const float* __restrict__ Wfc,
                                                  float* __restrict__ out)
{
    int t = threadIdx.x;
    int rr = t >> 6, cl = t & 63;
    int r = blockIdx.x * 4 + rr;
    float a0 = 0.f, a1 = 0.f;
    for (int k = 0; k < 128; k++) {
        float wv = Wv[r * 128 + k];
        a0 = fmaf(wv, Wfc[k * 128 + cl], a0);
        a1 = fmaf(wv, Wfc[k * 128 + 64 + cl], a1);
    }
    out[r * 128 + cl] = a0;
    out[r * 128 + 64 + cl] = a1;
}

// ---------------------------------------------------------------------------
// Split Bcat = [W1 | Wq] (stored [k][n] row-major) into bf16 hi/lo planes,
// TRANSPOSED: WT*[col][k], col 0..255 (0-127 = W1 cols, 128-255 = Wq cols).
// grid=128, block=256.
// ---------------------------------------------------------------------------
__global__ __launch_bounds__(256) void wsplit_prep_k(const float* __restrict__ W1,
                                                     const float* __restrict__ Wq,
                                                     unsigned short* __restrict__ WThi,
                                                     unsigned short* __restrict__ WTlo)
{
    int idx = blockIdx.x * 256 + threadIdx.x;   // 32768 total
    int col = idx >> 7, k = idx & 127;
    float w = (col < 128) ? W1[k * 128 + col] : Wq[k * 128 + (col - 128)];
    unsigned short hb = f2bf(w);
    float hf = bf2f(hb);
    WThi[col * 128 + k] = hb;
    WTlo[col * 128 + k] = f2bf(w - hf);
}

// ---------------------------------------------------------------------------
// MFMA dual GEMM via bf16 hi/lo split: C = gn1(X) @ [W1|Wq] with
//   C ~= Ahi@Bhi + Alo@Bhi + Ahi@Blo   (error ~1e-5 rel, near-fp32).
// grid=1024 (128 rows/block), block=512 (8 waves).
// ---------------------------------------------------------------------------
__global__ __launch_bounds__(512, 4) void gemm_mfma_dual(const float* __restrict__ X,
                                                         const unsigned short* __restrict__ WThi,
                                                         const unsigned short* __restrict__ WTlo,
                                                         const float* __restrict__ b1,
                                                         const float* __restrict__ stats,
                                                         float* __restrict__ C1,
                                                         float* __restrict__ C2,
                                                         float* __restrict__ statsout)
{
    __shared__ short sAhi[128 * 40];   // [row][k] bf16, stride 40 (pad)
    __shared__ short sAlo[128 * 40];
    __shared__ short sBhi[256 * 40];   // [col][k] bf16, stride 40
    __shared__ short sBlo[256 * 40];
    int t = threadIdx.x;
    int wv = t >> 6, lane = t & 63;
    int half = wv >> 2;                // 0 -> W1, 1 -> Wq
    int mrow0 = (wv & 3) * 32;
    long row0 = (long)blockIdx.x * 128;
    int bidx = (int)(row0 >> 14);

    float muv[4], rsv[4];
#pragma unroll
    for (int g = 0; g < 4; g++) {
        muv[g] = stats[(bidx * 4 + g) * 2];
        rsv[g] = stats[(bidx * 4 + g) * 2 + 1];
    }

    f32x4 acc[2][8];
#pragma unroll
    for (int m2 = 0; m2 < 2; m2++)
#pragma unroll
        for (int nt = 0; nt < 8; nt++) acc[m2][nt] = (f32x4){0.f, 0.f, 0.f, 0.f};

    int lr = lane & 15, lk = (lane >> 4) * 8;
    // staging assignments
    int arow = t >> 2, akq = (t & 3) * 8;        // A: 128 rows x 32 k, 8 elems/thr
    int bcol = t >> 1, bko = (t & 1) * 16;       // B: 256 cols x 32 k, 16 elems/thr/plane
    const float* xsrc = X + (row0 + arow) * 128;

    for (int kt = 0; kt < 4; kt++) {
        // ---- stage A (normalize, split hi/lo) ----
        {
            float mu = muv[kt], rs = rsv[kt];
            float4 x0 = *(const float4*)(xsrc + kt * 32 + akq);
            float4 x1 = *(const float4*)(xsrc + kt * 32 + akq + 4);
            float v[8];
            v[0] = x0.x; v[1] = x0.y; v[2] = x0.z; v[3] = x0.w;
            v[4] = x1.x; v[5] = x1.y; v[6] = x1.z; v[7] = x1.w;
            s16x8 vh, vl;
#pragma unroll
            for (int j = 0; j < 8; j++) {
                float x = (v[j] - mu) * rs;
                unsigned short hb = f2bf(x);
                float hf = bf2f(hb);
                unsigned short lb = f2bf(x - hf);
                vh[j] = (short)hb;
                vl[j] = (short)lb;
            }
            *(s16x8*)&sAhi[arow * 40 + akq] = vh;
            *(s16x8*)&sAlo[arow * 40 + akq] = vl;
        }
        // ---- stage B (copy pre-split planes) ----
        {
            const unsigned short* sh = WThi + bcol * 128 + kt * 32 + bko;
            const unsigned short* sl = WTlo + bcol * 128 + kt * 32 + bko;
            *(s16x8*)&sBhi[bcol * 40 + bko]     = *(const s16x8*)(sh);
            *(s16x8*)&sBhi[bcol * 40 + bko + 8] = *(const s16x8*)(sh + 8);
            *(s16x8*)&sBlo[bcol * 40 + bko]     = *(const s16x8*)(sl);
            *(s16x8*)&sBlo[bcol * 40 + bko + 8] = *(const s16x8*)(sl + 8);
        }
        __syncthreads();
        // ---- fragments + MFMA ----
        s16x8 ahi[2], alo[2];
#pragma unroll
        for (int m2 = 0; m2 < 2; m2++) {
            int row = mrow0 + m2 * 16 + lr;
            ahi[m2] = *(const s16x8*)&sAhi[row * 40 + lk];
            alo[m2] = *(const s16x8*)&sAlo[row * 40 + lk];
        }
#pragma unroll
        for (int nt = 0; nt < 8; nt++) {
            int col = half * 128 + nt * 16 + lr;
            s16x8 bhi = *(const s16x8*)&sBhi[col * 40 + lk];
            s16x8 blo = *(const s16x8*)&sBlo[col * 40 + lk];
#pragma unroll
            for (int m2 = 0; m2 < 2; m2++) {
                acc[m2][nt] = __builtin_amdgcn_mfma_f32_16x16x32_bf16(ahi[m2], bhi, acc[m2][nt], 0, 0, 0);
                acc[m2][nt] = __builtin_amdgcn_mfma_f32_16x16x32_bf16(alo[m2], bhi, acc[m2][nt], 0, 0, 0);
                acc[m2][nt] = __builtin_amdgcn_mfma_f32_16x16x32_bf16(ahi[m2], blo, acc[m2][nt], 0, 0, 0);
            }
        }
        __syncthreads();
    }

    // ---- epilogue: bias/leaky + store ----
    int rg4 = (lane >> 4) * 4;
    float* C = half ? C2 : C1;
    float bv[8];
    if (half == 0) {
#pragma unroll
        for (int nt = 0; nt < 8; nt++) bv[nt] = b1[nt * 16 + lr];
    }
#pragma unroll
    for (int m2 = 0; m2 < 2; m2++) {
        long rbase = row0 + mrow0 + m2 * 16 + rg4;
#pragma unroll
        for (int nt = 0; nt < 8; nt++) {
#pragma unroll
            for (int r = 0; r < 4; r++) {
                float v = acc[m2][nt][r];
                if (half == 0) {
                    v += bv[nt];
                    v = (v >= 0.f) ? v : 0.01f * v;
                }
                C[(rbase + r) * 128 + nt * 16 + lr] = v;
            }
        }
    }
    // ---- fused gn2 partial stats from the Wq half ----
    float s4[4] = {0.f, 0.f, 0.f, 0.f}, ss4[4] = {0.f, 0.f, 0.f, 0.f};
    if (half == 1) {
#pragma unroll
        for (int m2 = 0; m2 < 2; m2++)
#pragma unroll
            for (int nt = 0; nt < 8; nt++) {
                int g = nt >> 1;
#pragma unroll
                for (int r = 0; r < 4; r++) {
                    float v = acc[m2][nt][r];
                    s4[g] += v; ss4[g] += v * v;
                }
            }
    }
    __syncthreads();
    float* sRed = (float*)sAhi;   // 8 KB needed <= 10,240 B; sA dead
    if (half == 1) {
        int q = t & 255;
#pragma unroll
        for (int g = 0; g < 4; g++) {
            sRed[q * 8 + 2 * g]     = s4[g];
            sRed[q * 8 + 2 * g + 1] = ss4[g];
        }
    }
    __syncthreads();
    if (t < 8) {
        int g = t >> 1, which = t & 1;
        float a2 = 0.f;
        for (int u = 0; u < 256; u++) a2 += sRed[u * 8 + 2 * g + which];
        statsout[((bidx * 4 + g) * 128 + (int)(blockIdx.x & 127)) * 2 + which] = a2;
    }
}

// ---------------------------------------------------------------------------
// attn_v3: q = gn2(qraw) -> outQ (in place); S = sq_dist(q,q) via bf16 hi/lo
// MFMA Gram matrix; softmax + min-max -> af.
// grid=2048 (1 window/block), block=256 (4 waves).
// ---------------------------------------------------------------------------
__global__ __launch_bounds__(256, 3) void attn_v3(const float* __restrict__ Qraw,
                                                  const float* __restrict__ stats,
                                                  float* __restrict__ outQ,
                                                  float* __restrict__ outAF)
{
    __shared__ short sYhi[4 * 64 * 40];   // [kchunk][row][40]
    __shared__ short sYlo[4 * 64 * 40];
    __shared__ float sN[64];
    float* sS = (float*)sYlo;             // alias after MFMA: [row][68]
    int t = threadIdx.x;
    int wv = t >> 6, lane = t & 63;
    int w = blockIdx.x;
    int bidx = w >> 8;

    // ---- stage: row = t>>2, kchunk = t&3 (kchunk == gn group) ----
    {
        int row = t >> 2, kc = t & 3;
        float mu = stats[(bidx * 4 + kc) * 2];
        float rs = stats[(bidx * 4 + kc) * 2 + 1];
        const float* src = Qraw + (long)w * 8192 + row * 128 + kc * 32;
        float* dstG = outQ + (long)w * 8192 + row * 128 + kc * 32;
        s16x8 vh[4], vl[4];
        float n = 0.f;
#pragma unroll
        for (int q4 = 0; q4 < 8; q4++) {
            float4 v = *(const float4*)(src + 4 * q4);
            float vv[4] = {v.x, v.y, v.z, v.w};
            float4 o;
#pragma unroll
            for (int e = 0; e < 4; e++) {
                float x = (vv[e] - mu) * rs;
                (&o.x)[e] = x;
                n += x * x;
                unsigned short hb = f2bf(x);
                float hf = bf2f(hb);
                int kk = q4 * 4 + e;
                vh[kk >> 3][kk & 7] = (short)hb;
                vl[kk >> 3][kk & 7] = (short)f2bf(x - hf);
            }
            *(float4*)(dstG + 4 * q4) = o;
        }
        int base = (kc * 64 + row) * 40;
#pragma unroll
        for (int u = 0; u < 4; u++) {
            *(s16x8*)&sYhi[base + u * 8] = vh[u];
            *(s16x8*)&sYlo[base + u * 8] = vl[u];
        }
        // quad-reduce the row norm (lanes 4r..4r+3 share a row)
        n += __shfl_xor(n, 1);
        n += __shfl_xor(n, 2);
        if (kc == 0) sN[row] = n;
    }
    __syncthreads();

    // ---- Gram via MFMA: wave wv owns rows wv*16..+15, 4 col-tiles ----
    f32x4 acc[4];
#pragma unroll
    for (int nt = 0; nt < 4; nt++) acc[nt] = (f32x4){0.f, 0.f, 0.f, 0.f};
    int lr = lane & 15, lk = (lane >> 4) * 8;
    for (int kc = 0; kc < 4; kc++) {
        int abase = (kc * 64 + wv * 16 + lr) * 40 + lk;
        s16x8 ahi = *(const s16x8*)&sYhi[abase];
        s16x8 alo = *(const s16x8*)&sYlo[abase];
#pragma unroll
        for (int nt = 0; nt < 4; nt++) {
            int bbase = (kc * 64 + nt * 16 + lr) * 40 + lk;
            s16x8 bhi = *(const s16x8*)&sYhi[bbase];
            s16x8 blo = *(const s16x8*)&sYlo[bbase];
            acc[nt] = __builtin_amdgcn_mfma_f32_16x16x32_bf16(ahi, bhi, acc[nt], 0, 0, 0);
            acc[nt] = __builtin_amdgcn_mfma_f32_16x16x32_bf16(alo, bhi, acc[nt], 0, 0, 0);
            acc[nt] = __builtin_amdgcn_mfma_f32_16x16x32_bf16(ahi, blo, acc[nt], 0, 0, 0);
        }
    }
    __syncthreads();   // all waves done reading sYlo before aliasing

    // ---- S = n_r + n_c - 2*dot -> sS[row][68] ----
    {
        float nrow[4];
        int r0 = wv * 16 + (lane >> 4) * 4;
#pragma unroll
        for (int r = 0; r < 4; r++) nrow[r] = sN[r0 + r];
#pragma unroll
        for (int nt = 0; nt < 4; nt++) {
            float ncol = sN[nt * 16 + lr];
#pragma unroll
            for (int r = 0; r < 4; r++)
                sS[(r0 + r) * 68 + nt * 16 + lr] = nrow[r] + ncol - 2.f * acc[nt][r];
        }
    }
    __syncthreads();

    // ---- epilogue: 4 threads/row, single read pass, regs thereafter ----
    {
        int row = t >> 2, j0 = (t & 3) * 16;
        float p[16];
#pragma unroll
        for (int q = 0; q < 4; q++) {
            float4 v = *(const float4*)&sS[row * 68 + j0 + 4 * q];
            p[4 * q + 0] = v.x; p[4 * q + 1] = v.y;
            p[4 * q + 2] = v.z; p[4 * q + 3] = v.w;
        }
        float mn = p[0];
#pragma unroll
        for (int i = 1; i < 16; i++) mn = fminf(mn, p[i]);
        mn = fminf(mn, __shfl_xor(mn, 1));
        mn = fminf(mn, __shfl_xor(mn, 2));
        float sum = 0.f, pmx = -1.f, pmn = 1e30f;
#pragma unroll
        for (int i = 0; i < 16; i++) {
            float e = expf(-SCL_F * (p[i] - mn));
            p[i] = e;
            sum += e;
            pmx = fmaxf(pmx, e);
            pmn = fminf(pmn, e);
        }
        sum += __shfl_xor(sum, 1); sum += __shfl_xor(sum, 2);
        pmx = fmaxf(pmx, __shfl_xor(pmx, 1)); pmx = fmaxf(pmx, __shfl_xor(pmx, 2));
        pmn = fminf(pmn, __shfl_xor(pmn, 1)); pmn = fminf(pmn, __shfl_xor(pmn, 2));
        float rsum = 1.0f / sum;
        float amn = pmn * rsum, amx = pmx * rsum;
        float dinv = 1.0f / (amx - amn + 1e-8f);
        float* dst = outAF + (long)w * 4096 + row * 64 + j0;
#pragma unroll
        for (int q = 0; q < 4; q++) {
            float4 o;
            o.x = (p[4 * q + 0] * rsum - amn) * dinv;
            o.y = (p[4 * q + 1] * rsum - amn) * dinv;
            o.z = (p[4 * q + 2] * rsum - amn) * dinv;
            o.w = (p[4 * q + 3] * rsum - amn) * dinv;
            *(float4*)(dst + 4 * q) = o;
        }
    }
}

// ---------------------------------------------------------------------------
// Per-window clustering, register/readlane rewrite (DS-minimized).
// grid=2048, block=256.
// ---------------------------------------------------------------------------
__global__ __launch_bounds__(256, 4) void cluster_v3(const float* __restrict__ AF,
                                                     const float* __restrict__ GEO,
                                                     float* __restrict__ oCLM,
                                                     float* __restrict__ oCLR,
                                                     float* __restrict__ oCOMP,
                                                     float* __restrict__ oGEO,
                                                     float* __restrict__ oSCM,
                                                     float* __restrict__ wCLMM)
{
    __shared__ float sAF[64 * 65];
    __shared__ float sPart[4 * 64 * 3];
    __shared__ float sCLM[8 * 65];
    int t = threadIdx.x, w = blockIdx.x;
    int wv = t >> 6, lane = t & 63;
    const float* afw = AF + (long)w * 4096;
#pragma unroll
    for (int i = 0; i < 4; i++) {
        int f4 = i * 256 + t;
        float4 v = *(const float4*)(afw + f4 * 4);
        int r = f4 >> 4, c4 = (f4 & 15) * 4;
        float* dst = &sAF[r * 65 + c4];
        dst[0] = fminf(fmaxf(v.x, 1e-5f), 0.99999f);
        dst[1] = fminf(fmaxf(v.y, 1e-5f), 0.99999f);
        dst[2] = fminf(fmaxf(v.z, 1e-5f), 0.99999f);
        dst[3] = fminf(fmaxf(v.w, 1e-5f), 0.99999f);
    }
    // per-lane geo row (lane = element index)
    const float* gp = GEO + ((long)w * 64 + lane) * 6;
    float2 g01 = *(const float2*)(gp);
    float2 g23 = *(const float2*)(gp + 2);
    float2 g45 = *(const float2*)(gp + 4);
    float gD = g01.x, gA = g23.x, gI = g23.y, gX = g45.x, gY = g45.y;
    __syncthreads();

    // ---- phase 1 ----
    const float* afrow = &sAF[lane * 65];
    float dk[16], ak[16], T[16];
    float v0 = 0.f, v1 = 0.f;
#pragma unroll
    for (int kk = 0; kk < 16; kk++) {
        int kc = kk * 4 + wv;
        float afk = afrow[kc];
        float d = afk * rlane(gD, kc);
        float a = afk * rlane(gA, kc);
        dk[kk] = d; ak[kk] = a; T[kk] = 0.f;
        float m = d * a;
        float dx = gX - rlane(gX, kc), dy = gY - rlane(gY, kc);
        v0 += d * rlane(gI, kc) + m * (dx * dx + dy * dy);
        v1 += m * a;
    }
    for (int jq = 0; jq < 16; jq++) {
        float dj[4], aj[4];
#pragma unroll
        for (int jr = 0; jr < 4; jr++) {
            int j = jq * 4 + jr;
            float afj = afrow[j];
            dj[jr] = afj * rlane(gD, j);
            aj[jr] = afj * rlane(gA, j);
        }
#pragma unroll
        for (int kk = 0; kk < 16; kk++) {
            if (kk > jq) {
#pragma unroll
                for (int jr = 0; jr < 4; jr++)
                    T[kk] = fmaf(aj[jr], fminf(dj[jr], dk[kk]), T[kk]);
            } else if (kk == jq) {
                if (0 < wv) T[kk] = fmaf(aj[0], fminf(dj[0], dk[kk]), T[kk]);
                if (1 < wv) T[kk] = fmaf(aj[1], fminf(dj[1], dk[kk]), T[kk]);
                if (2 < wv) T[kk] = fmaf(aj[2], fminf(dj[2], dk[kk]), T[kk]);
            }
        }
    }
    float S = 0.f;
#pragma unroll
    for (int kk = 0; kk < 16; kk++) S = fmaf(ak[kk], T[kk], S);
    {
        float* p = &sPart[(wv * 64 + lane) * 3];
        p[0] = v0; p[1] = v1; p[2] = S;
    }
    __syncthreads();

    // ---- combine + greedy selection (wave 0) ----
    if (t < 64) {
        int k = lane;
        float c0 = 0.f, c1 = 0.f, c2 = 0.f;
#pragma unroll
        for (int u = 0; u < 4; u++) {
            const float* p = &sPart[(u * 64 + k) * 3];
            c0 += p[0]; c1 += p[1]; c2 += p[2];
        }
        float compk = ((c1 + 2.f * c2) / TWO_PI_F) / c0;
        float sc = 1.0f;
        for (int c = 0; c < 7; c++) {
            float score = compk * sc;
            float mx = score;
            for (int off = 1; off < 64; off <<= 1) mx = fmaxf(mx, __shfl_xor(mx, off));
            unsigned long long bl = __ballot(score == mx);
            int idx = __ffsll(bl) - 1;
            float rowk = sAF[idx * 65 + k];
            float clm = sc * rowk;
            sCLM[c * 65 + k] = clm;
            oCLM[(long)w * 512 + c * 64 + k] = clm;
            if (k == 0) oCLR[(long)w * 7 + c] = (float)idx;
            sc *= (1.0f - rowk);
        }
        sCLM[7 * 65 + k] = sc;
        oCLM[(long)w * 512 + 448 + k] = sc;
        oSCM[(long)w * 64 + k] = sc;
    }
    __syncthreads();

    // ---- phase 3: cluster aggregates + second compactness (2 clusters/wave) ----
    {
        int k = lane;
        for (int cc = 0; cc < 2; cc++) {
            int c = wv + cc * 4;
            float clm = sCLM[c * 65 + k];
            float cd = clm * gD, ca = clm * gA;
            float cm = cd * ca;
            float T3 = 0.f;
            for (int j = 0; j < 64; j++)
                T3 = fmaf(rlane(ca, j), fminf(rlane(cd, j), cd), T3);
            float r0 = cm, r1 = ca, r2c = cm * gX, r3 = cm * gY, r4 = clm;
            float r5 = cm * ca;
            float r6 = ca * T3 - ca * ca * cd;   // 2*S contribution (self removed)
            for (int off = 1; off < 64; off <<= 1) {
                r0 += __shfl_xor(r0, off); r1 += __shfl_xor(r1, off);
                r2c += __shfl_xor(r2c, off); r3 += __shfl_xor(r3, off);
                r4 += __shfl_xor(r4, off); r5 += __shfl_xor(r5, off);
                r6 += __shfl_xor(r6, off);
            }
            float mass = r0, area = r1;
            float qx = r2c / (mass + 1e-8f), qy = r3 / (mass + 1e-8f);
            wCLMM[(long)w * 512 + c * 64 + k] = clm / (r4 + 1e-8f);
            float dx = qx - gX, dy = qy - gY;
            float w0v = cd * gI + cm * (dx * dx + dy * dy);
            for (int off = 1; off < 64; off <<= 1) w0v += __shfl_xor(w0v, off);
            if (k == 0) {
                oCOMP[(long)w * 8 + c] = ((r5 + r6) / TWO_PI_F) / w0v;
                float* og = oGEO + (long)w * 48 + c * 6;
                og[0] = mass / (area + 1e-8f); og[1] = mass; og[2] = area;
                og[3] = w0v; og[4] = qx; og[5] = qy;
            }
        }
    }
}

// ---------------------------------------------------------------------------
// final_v4: cl_f = t1*sigma + sc*(mu+b2) + bfc + u@W2 + t1@Wvf.
// VALU-debloat of final_v3: broadcasts moved off the VALU pipe.
//  - stage 1: mm[c][j] loaded as wave-uniform float4 from global (lane-
//    invariant address -> s_load_dwordx4); no readlanes.
//  - stage 2: x[c][k] read as wave-uniform ds_read_b128 from sU/sT
//    (stride 132 for 16B alignment); no readlanes, no xL preload.
//  - t1*sigma uses acc1[c] (the lane's own t1 value) directly.
// grid=2048, block=256.
// ---------------------------------------------------------------------------
__global__ __launch_bounds__(256, 4) void final_v4(const float* __restrict__ inF,
                                                   const float* __restrict__ H1,
                                                   const float* __restrict__ CLMM,
                                                   const float* __restrict__ stats1,
                                                   const float* __restrict__ W2,
                                                   const float* __restrict__ b2,
                                                   const float* __restrict__ Wvf,
                                                   const float* __restrict__ bfc,
                                                   float* __restrict__ oCLF)
{
    __shared__ __align__(16) float sU[8 * 132];
    __shared__ __align__(16) float sT[8 * 132];
    __shared__ __align__(16) float sP[8 * 132];
    int t = threadIdx.x, w = blockIdx.x;
    int bidx = w >> 8;
    int wv = t >> 6, lane = t & 63;
    int ch = lane + 64 * (wv & 1);

    float mu = stats1[(bidx * 4 + (ch >> 5)) * 2];
    float rs = stats1[(bidx * 4 + (ch >> 5)) * 2 + 1];

    const float* mmw = CLMM + (long)w * 512;   // [c][j], lane-invariant reads

    // ---- stage 1: K=64 GEMVs, mm via wave-uniform loads ----
    float acc1[8];
#pragma unroll
    for (int c = 0; c < 8; c++) acc1[c] = 0.f;
    if (wv < 2) {
        const float* src = H1 + (long)w * 8192 + ch;
        for (int j0 = 0; j0 < 64; j0 += 4) {
            float f0 = src[(j0 + 0) * 128];
            float f1 = src[(j0 + 1) * 128];
            float f2 = src[(j0 + 2) * 128];
            float f3 = src[(j0 + 3) * 128];
#pragma unroll
            for (int c = 0; c < 8; c++) {
                float4 m = *(const float4*)&mmw[c * 64 + j0];
                acc1[c] = fmaf(m.x, f0, acc1[c]);
                acc1[c] = fmaf(m.y, f1, acc1[c]);
                acc1[c] = fmaf(m.z, f2, acc1[c]);
                acc1[c] = fmaf(m.w, f3, acc1[c]);
            }
        }
#pragma unroll
        for (int c = 0; c < 8; c++) sU[c * 132 + ch] = acc1[c];
    } else {
        const float* src = inF + (long)w * 8192 + ch;
        for (int j0 = 0; j0 < 64; j0 += 4) {
            float f0 = (src[(j0 + 0) * 128] - mu) * rs;
            float f1 = (src[(j0 + 1) * 128] - mu) * rs;
            float f2 = (src[(j0 + 2) * 128] - mu) * rs;
            float f3 = (src[(j0 + 3) * 128] - mu) * rs;
#pragma unroll
            for (int c = 0; c < 8; c++) {
                float4 m = *(const float4*)&mmw[c * 64 + j0];
                acc1[c] = fmaf(m.x, f0, acc1[c]);
                acc1[c] = fmaf(m.y, f1, acc1[c]);
                acc1[c] = fmaf(m.z, f2, acc1[c]);
                acc1[c] = fmaf(m.w, f3, acc1[c]);
            }
        }
#pragma unroll
        for (int c = 0; c < 8; c++) sT[c * 132 + ch] = acc1[c];
    }
    __syncthreads();

    // ---- stage 2: K=128 GEMVs, x via wave-uniform ds_read_b128 ----
    const float* Wm = (wv < 2) ? W2 : Wvf;
    const float* s2 = (wv < 2) ? sU : sT;
    float acc2[8];
#pragma unroll
    for (int c = 0; c < 8; c++) acc2[c] = 0.f;
    for (int k0 = 0; k0 < 128; k0 += 4) {
        float w0 = Wm[(k0 + 0) * 128 + ch];
        float w1 = Wm[(k0 + 1) * 128 + ch];
        float w2v = Wm[(k0 + 2) * 128 + ch];
        float w3 = Wm[(k0 + 3) * 128 + ch];
#pragma unroll
        for (int c = 0; c < 8; c++) {
            float4 x = *(const float4*)&s2[c * 132 + k0];
            acc2[c] = fmaf(x.x, w0, acc2[c]);
            acc2[c] = fmaf(x.y, w1, acc2[c]);
            acc2[c] = fmaf(x.z, w2v, acc2[c]);
            acc2[c] = fmaf(x.w, w3, acc2[c]);
        }
    }
    if (wv >= 2) {
        // + t1 * sigma  (acc1[c] IS t1[c][ch] for this lane)
        float sig = 1.0f / rs;
#pragma unroll
        for (int c = 0; c < 8; c++) acc2[c] = fmaf(acc1[c], sig, acc2[c]);
#pragma unroll
        for (int c = 0; c < 8; c++) sP[c * 132 + ch] = acc2[c];
    }
    __syncthreads();
    if (wv < 2) {
        // scv[c] = sum_j mm[c][j] via per-lane load + shfl reduce
        float scv[8];
#pragma unroll
        for (int c = 0; c < 8; c++) {
            float s = mmw[c * 64 + lane];
            for (int off = 1; off < 64; off <<= 1) s += __shfl_xor(s, off);
            scv[c] = s;
        }
        float mub = mu + b2[ch];
        float bfv = bfc[ch];
#pragma unroll
        for (int c = 0; c < 8; c++) {
            float o = acc2[c] + sP[c * 132 + ch] + scv[c] * mub + bfv;
            oCLF[(long)w * 1024 + c * 128 + ch] = o;
        }
    }
}

// ---------------------------------------------------------------------------
extern "C" void kernel_launch(void* const* d_in, const int* in_sizes, int n_in,
                              void* d_out, int out_size, void* d_ws, size_t ws_size,
                              hipStream_t stream)
{
    (void)in_sizes; (void)n_in; (void)out_size; (void)ws_size;
    const float* in_f   = (const float*)d_in[0];
    const float* in_geo = (const float*)d_in[1];
    const float* W1  = (const float*)d_in[2];
    const float* b1  = (const float*)d_in[3];
    const float* W2  = (const float*)d_in[4];
    const float* b2  = (const float*)d_in[5];
    const float* Wfc = (const float*)d_in[6];
    const float* bfc = (const float*)d_in[7];
    const float* Wq  = (const float*)d_in[8];
    const float* Wv  = (const float*)d_in[9];
    float* out = (float*)d_out;
    float* ws  = (float*)d_ws;

    // workspace (floats)
    float* qh     = ws;                    // 16,777,216 (h1)
    float* clmm   = ws + 16777216;         //  1,048,576 (WThi/WTlo early, then clmm)
    float* stats1 = ws + 17825792;         //  64
    float* stats2 = ws + 17825856;         //  64
    float* wvf    = ws + 17825920;         //  16,384
    float* part   = ws + 17842304;         //  8,192

    // WT hi/lo bf16 planes (256 cols x 128 k, ushort) stashed in clmm region:
    // consumed by gemm_mfma_dual (dispatch 5) before cluster_v3 (dispatch 8)
    // overwrites clmm.
    unsigned short* wthi = (unsigned short*)clmm;            // 65,536 B
    unsigned short* wtlo = ((unsigned short*)clmm) + 32768;  // 65,536 B

    // output layout (floats)
    float* o_clf  = out;                   // (8,256,8,128)
    float* o_clm  = out + 2097152;         // (8,256,8,64)
    float* o_geo  = out + 3145728;         // (8,256,8,6)
    float* o_clr  = out + 3244032;         // (8,256,7,1)
    float* o_comp = out + 3258368;         // (8,256,8,1)
    float* o_af   = out + 3274752;         // (8,256,64,64)
    float* o_scm  = out + 11663360;        // (8,256,1,64)
    float* o_q    = out + 11794432;        // (8,256,64,128)

    gn_partial_k<<<dim3(64, 32), 256, 0, stream>>>(in_f, part);
    gn_final_k<<<32, 64, 0, stream>>>(part, stats1, 64);
    wvf_prep_k<<<32, 256, 0, stream>>>(Wv, Wfc, wvf);
    wsplit_prep_k<<<128, 256, 0, stream>>>(W1, Wq, wthi, wtlo);
    // h1 = leaky(gn1(in_f)@W1 + b1) -> qh;  qraw = gn1(in_f)@Wq -> o_q (+stats2 partials)
    gemm_mfma_dual<<<1024, 512, 0, stream>>>(in_f, wthi, wtlo, b1, stats1, qh, o_q, part);
    gn_final_k<<<32, 64, 0, stream>>>(part, stats2, 128);
    // attn normalizes qraw IN PLACE in o_q and emits af
    attn_v3<<<2048, 256, 0, stream>>>(o_q, stats2, o_q, o_af);
    cluster_v3<<<2048, 256, 0, stream>>>(o_af, in_geo, o_clm, o_clr, o_comp, o_geo,
                                         o_scm, clmm);
    final_v4<<<2048, 256, 0, stream>>>(in_f, qh, clmm, stats1, W2, b2, wvf, bfc, o_clf);
}